// Round 1
// baseline (765.238 us; speedup 1.0000x reference)
//
#include <hip/hip_runtime.h>
#include <math.h>

typedef __bf16 bf16;
typedef __attribute__((ext_vector_type(8))) __bf16 bf16x8;
typedef __attribute__((ext_vector_type(4))) float f32x4;

// ---------------- workspace layout (bytes) ----------------
constexpr size_t OFF_CATSEQ = 0;          // 8*1024*1024*2 = 16777216  [b][p][c(0:512 vi,512:1024 ir)] bf16
constexpr size_t OFF_WBF    = 16777216;   // 4*262144*2               Wq,Wk,Wv,Wo bf16 [co][c]
constexpr size_t OFF_ENHW   = 18874368;   // 9*262144*2               enh_w repacked [t][co][ci] bf16
constexpr size_t OFF_GW1R   = 23592960;   // 9*32768*2                gate_w1 repacked [t][hid][ci] bf16
constexpr size_t OFF_CHS    = 24182784;   // 512*2*4                  bn scale[512], shift[512]
constexpr size_t OFF_ZP     = 24186880;   // 256                      zero page
constexpr size_t OFF_POOL   = 24187136;   // 8*512*4
constexpr size_t OFF_HID    = 24203520;   // 8*2048*4
constexpr size_t OFF_KW     = 24269056;   // 8*32*4
constexpr size_t OFF_Q      = 24270080;   // 8388608  [b][h][p][d] bf16 (x0.125)
constexpr size_t OFF_K      = 32658688;   // 8388608  [b][h][p][d] bf16
constexpr size_t OFF_VT     = 41047296;   // 8388608  [b][h][d][p] bf16
constexpr size_t OFF_CTX    = 49435904;   // 8388608  [b][p][c] bf16
constexpr size_t OFF_FF     = 57824512;   // 8388608  fused_feat [b][c][p] bf16
constexpr size_t OFF_G1P    = 66213120;   // 9437184  gate1 partials [t][b][32][1024] f32
constexpr size_t OFF_Y1     = 75650304;   // 1048576  y1 [b][32][1024] f32
constexpr size_t OFF_GSUM   = 76698880;   // 32768    [b][p] f32
constexpr size_t OFF_F2     = 76731648;   // 8388608  fused2 [b][p][c] bf16
// total 85120256 bytes

struct KParams {
  const float *vi, *ir, *bq, *bk, *bv, *bo, *gb1;
  char* ws;
  float* out;
};

__device__ __forceinline__ void gload16(const void* g, void* l) {
  __builtin_amdgcn_global_load_lds(
      (const __attribute__((address_space(1))) unsigned int*)g,
      (__attribute__((address_space(3))) unsigned int*)l, 16, 0, 0);
}

// ---------------- weight prep: casts, repacks, bn-fold, zero page ----------------
__global__ void k_wprep(const float* Wq, const float* Wk, const float* Wv, const float* Wo,
                        const float* enh_w, const float* gw1,
                        const float* enh_b, const float* gamma, const float* beta,
                        const float* mean, const float* var,
                        bf16* wbf, bf16* enhw, bf16* gw1r, float* chs, float* zp)
{
  long i = (long)blockIdx.x*256 + threadIdx.x;
  if (i < 1048576) {
    int which = (int)(i >> 18); long r = i & 262143;
    const float* s = which==0?Wq: which==1?Wk: which==2?Wv:Wo;
    wbf[i] = (bf16)s[r];
  } else if (i < 1048576+2359296) {
    long j = i - 1048576; long t = j/262144; long r = j%262144;   // r = co*512+ci
    enhw[j] = (bf16)enh_w[r*9 + t];
  } else if (i < 1048576+2359296+294912) {
    long j = i - (1048576+2359296); long t = j/32768; long r = j%32768; // r = hid*1024+ci
    gw1r[j] = (bf16)gw1[r*9 + t];
  } else if (i < 1048576+2359296+294912+512) {
    int c = (int)(i - (1048576+2359296+294912));
    float sc = gamma[c]*rsqrtf(var[c]+1e-5f);
    chs[c] = sc; chs[512+c] = (enh_b[c]-mean[c])*sc + beta[c];
  } else if (i < 1048576+2359296+294912+512+64) {
    zp[i - (1048576+2359296+294912+512)] = 0.f;
  }
}

// ---------------- transpose-cast vi/ir -> catseq[b][p][1024] bf16 ----------------
__global__ __launch_bounds__(256) void k_cat(const float* vi, const float* ir, bf16* cat)
{
  __shared__ float ld[32][129];
  int pt = blockIdx.x, ct = blockIdx.y, b = blockIdx.z;
  const float* src = (ct < 16) ? vi : ir;
  int c0 = (ct & 15) * 32;
  int tid = threadIdx.x;
  int p0 = pt * 128;
  for (int it = 0; it < 4; ++it) {
    int row = it*8 + (tid>>5);
    int pc  = (tid & 31) * 4;
    float4 v = *(const float4*)(src + ((long)(b*512 + c0 + row))*1024 + p0 + pc);
    ld[row][pc+0]=v.x; ld[row][pc+1]=v.y; ld[row][pc+2]=v.z; ld[row][pc+3]=v.w;
  }
  __syncthreads();
  int p = tid >> 1, half = tid & 1;
  bf16x8 o0, o1;
  #pragma unroll
  for (int j = 0; j < 8; ++j) o0[j] = (bf16)ld[half*16 + j][p];
  #pragma unroll
  for (int j = 0; j < 8; ++j) o1[j] = (bf16)ld[half*16 + 8 + j][p];
  long ccol = (ct<16 ? 0 : 512) + c0 + half*16;
  bf16* dst = cat + ((long)(b*1024 + p0 + p))*1024 + ccol;
  *(bf16x8*)dst       = o0;
  *((bf16x8*)dst + 1) = o1;
}

// ---------------- pooled[b][c] ----------------
__global__ __launch_bounds__(256) void k_pool(const float* vi, const float* ir, float* pooled)
{
  int bc = blockIdx.x;
  int tid = threadIdx.x;
  float4 a = ((const float4*)(vi + (long)bc*1024))[tid];
  float4 c = ((const float4*)(ir + (long)bc*1024))[tid];
  float s = a.x+a.y+a.z+a.w + c.x+c.y+c.z+c.w;
  #pragma unroll
  for (int off=32; off; off>>=1) s += __shfl_down(s, off);
  __shared__ float wsum[4];
  if ((tid&63)==0) wsum[tid>>6] = s;
  __syncthreads();
  if (tid==0) pooled[bc] = (wsum[0]+wsum[1]+wsum[2]+wsum[3]) * (1.f/1024.f);
}

// ---------------- mlp1: hid = relu(pooled @ w1^T + b1) ----------------
__global__ __launch_bounds__(256) void k_mlp1(const float* pooled, const float* w1, const float* b1, float* hid)
{
  __shared__ float pl[512];
  int blk = blockIdx.x; int b = blk >> 3, ch = blk & 7;
  int tid = threadIdx.x;
  ((float2*)pl)[tid] = ((const float2*)(pooled + b*512))[tid];
  __syncthreads();
  int i = ch*256 + tid;
  const float* wr = w1 + (long)i*512;
  float acc = b1[i];
  #pragma unroll 8
  for (int c = 0; c < 512; ++c) acc += pl[c]*wr[c];
  hid[b*2048 + i] = fmaxf(acc, 0.f);
}

// ---------------- mlp2 + softmax -> kw[b][25] ----------------
__global__ __launch_bounds__(256) void k_mlp2(const float* hid, const float* w2, const float* b2, float* kw)
{
  __shared__ float hd[2048];
  __shared__ float lg[32];
  int b = blockIdx.x, tid = threadIdx.x, lane = tid&63, wave = tid>>6;
  ((float2*)hd)[tid]     = ((const float2*)(hid + b*2048))[tid];
  ((float2*)hd)[tid+256] = ((const float2*)(hid + b*2048))[tid+256];
  __syncthreads();
  for (int j = wave; j < 25; j += 4) {
    const float* wr = w2 + (long)j*2048;
    float acc = 0;
    for (int i = lane; i < 2048; i += 64) acc += hd[i]*wr[i];
    #pragma unroll
    for (int off=32; off; off>>=1) acc += __shfl_down(acc, off);
    if (lane==0) lg[j] = acc + b2[j];
  }
  __syncthreads();
  if (tid==0) {
    float mx = lg[0];
    for (int j=1;j<25;++j) mx = fmaxf(mx, lg[j]);
    float s = 0.f; float e[25];
    for (int j=0;j<25;++j){ e[j]=__expf(lg[j]-mx); s+=e[j]; }
    float inv = 1.f/s;
    for (int j=0;j<25;++j) kw[b*32+j] = e[j]*inv;
  }
}

// ---------------- generic TN bf16 MFMA GEMM ----------------
// OP 0: QKV   (z = b*3+which)  D[co][p] -> Q/K p-major, V d-major
// OP 1: Wo    (z = b)          D[co][p] -> fused_feat bf16
// OP 2: enh   (z = b)          conv-as-GEMM 9 taps, BN+SiLU -> out f32
// OP 3: gate1 (z = tap*8+b)    tap partial -> g1part f32
template<int OP, int BM, int BN, int WAVES_M, int KSTEPS>
__global__ __launch_bounds__(256)
void k_gemm(KParams p)
{
  constexpr int WAVES_N = 4/WAVES_M;
  constexpr int MT = BM/(WAVES_M*16);
  constexpr int NT = BN/(WAVES_N*16);
  __shared__ bf16 As[BM*32];
  __shared__ bf16 Bs[BN*32];
  const int tid = threadIdx.x, lane = tid&63, wave = tid>>6;
  const int g = lane>>4, l15 = lane&15;
  const int wm = wave % WAVES_M, wn = wave / WAVES_M;

  int b, which = 0, tap = 0, m0, n0;
  const bf16 *Aptr, *Bptr;
  long ldb, lda;
  if constexpr (OP==0) {
    b = blockIdx.z/3; which = blockIdx.z%3;
    m0 = blockIdx.y*BM; n0 = blockIdx.x*BN;
    Aptr = (const bf16*)(p.ws+OFF_WBF) + (long)which*262144;
    Bptr = (const bf16*)(p.ws+OFF_CATSEQ) + (long)b*1048576 + (which?512:0);
    ldb = 1024; lda = 512;
  } else if constexpr (OP==1) {
    b = blockIdx.z; m0 = blockIdx.y*BM; n0 = blockIdx.x*BN;
    Aptr = (const bf16*)(p.ws+OFF_WBF) + 3L*262144;
    Bptr = (const bf16*)(p.ws+OFF_CTX) + (long)b*524288;
    ldb = 512; lda = 512;
  } else if constexpr (OP==2) {
    b = blockIdx.z; m0 = blockIdx.y*BM; n0 = blockIdx.x*BN;
    Aptr = (const bf16*)(p.ws+OFF_ENHW);
    Bptr = (const bf16*)(p.ws+OFF_F2) + (long)b*524288;
    ldb = 512; lda = 512;
  } else {
    tap = blockIdx.z>>3; b = blockIdx.z&7;
    m0 = 0; n0 = blockIdx.x*BN;
    Aptr = (const bf16*)(p.ws+OFF_GW1R) + (long)tap*32768;
    Bptr = (const bf16*)(p.ws+OFF_CATSEQ) + (long)b*1048576;
    ldb = 1024; lda = 1024;
  }
  const bf16* zp = (const bf16*)(p.ws+OFF_ZP);

  f32x4 acc[MT][NT] = {};

  for (int ks = 0; ks < KSTEPS; ++ks) {
    int t, kc;
    if constexpr (OP==2) { t = ks/16; kc = ks%16; }
    else if constexpr (OP==3) { t = tap; kc = ks; }
    else { t = 0; kc = ks; }
    __syncthreads();
    // stage A (16B chunks, src-side XOR swizzle so frag ds_read_b128 is ~2-way)
    for (int c = tid; c < BM*4; c += 256) {
      int row = c>>2, slot = c&3;
      int ss = slot ^ ((row>>1)&3);
      const bf16* src;
      if constexpr (OP==2) src = Aptr + (long)t*262144 + (long)(m0+row)*lda + kc*32 + ss*8;
      else                 src = Aptr + (long)(m0+row)*lda + kc*32 + ss*8;
      gload16(src, As + (long)(c-lane)*8);
    }
    // stage B (with tap shift + border mask for conv ops)
    for (int c = tid; c < BN*4; c += 256) {
      int row = c>>2, slot = c&3;
      int ss = slot ^ ((row>>1)&3);
      const bf16* src;
      if constexpr (OP==2 || OP==3) {
        int pp = n0 + row;
        int hh = (pp>>5) + t/3 - 1, ww = (pp&31) + t%3 - 1;
        bool valid = ((unsigned)hh < 32u) && ((unsigned)ww < 32u);
        src = valid ? (Bptr + (long)(hh*32+ww)*ldb + kc*32 + ss*8) : zp;
      } else {
        src = Bptr + (long)(n0+row)*ldb + kc*32 + ss*8;
      }
      gload16(src, Bs + (long)(c-lane)*8);
    }
    __syncthreads();
    bf16x8 af[MT], bq_[NT];
    #pragma unroll
    for (int mt=0; mt<MT; ++mt) {
      int row = wm*MT*16 + mt*16 + l15;
      af[mt] = *(const bf16x8*)&As[row*32 + 8*(g ^ ((row>>1)&3))];
    }
    #pragma unroll
    for (int nt=0; nt<NT; ++nt) {
      int row = wn*NT*16 + nt*16 + l15;
      bq_[nt] = *(const bf16x8*)&Bs[row*32 + 8*(g ^ ((row>>1)&3))];
    }
    #pragma unroll
    for (int mt=0; mt<MT; ++mt)
      #pragma unroll
      for (int nt=0; nt<NT; ++nt)
        acc[mt][nt] = __builtin_amdgcn_mfma_f32_16x16x32_bf16(af[mt], bq_[nt], acc[mt][nt], 0,0,0);
  }

  // epilogue (D: row m = 4*(lane>>4)+reg, col n = lane&15)
  #pragma unroll
  for (int mt=0; mt<MT; ++mt) {
    #pragma unroll
    for (int nt=0; nt<NT; ++nt) {
      #pragma unroll
      for (int reg=0; reg<4; ++reg) {
        int m = m0 + wm*MT*16 + mt*16 + 4*g + reg;
        int n = n0 + wn*NT*16 + nt*16 + l15;
        float v = acc[mt][nt][reg];
        if constexpr (OP==0) {
          const float* bias = which==0?p.bq: which==1?p.bk:p.bv;
          v += bias[m];
          if (which==0) v *= 0.125f;
          int h = m>>6, d = m&63;
          if (which==2) ((bf16*)(p.ws+OFF_VT))[((long)(b*8+h)*64 + d)*1024 + n] = (bf16)v;
          else {
            bf16* dst = (bf16*)(p.ws + (which==0?OFF_Q:OFF_K));
            dst[((long)(b*8+h)*1024 + n)*64 + d] = (bf16)v;
          }
        } else if constexpr (OP==1) {
          v += p.bo[m];
          ((bf16*)(p.ws+OFF_FF))[((long)(b*512+m))*1024 + n] = (bf16)v;
        } else if constexpr (OP==2) {
          const float* chs = (const float*)(p.ws+OFF_CHS);
          float yn = v*chs[m] + chs[512+m];
          p.out[((long)(b*512+m))*1024 + n] = yn * (1.f/(1.f+__expf(-yn)));
        } else {
          ((float*)(p.ws+OFF_G1P))[((long)((tap*8+b)*32+m))*1024 + n] = v;
        }
      }
    }
  }
}

// ---------------- flash attention ----------------
__global__ __launch_bounds__(256)
void k_attn(KParams p)
{
  const bf16* Q = (const bf16*)(p.ws+OFF_Q);
  const bf16* K = (const bf16*)(p.ws+OFF_K);
  const bf16* V = (const bf16*)(p.ws+OFF_VT);
  bf16* ctx = (bf16*)(p.ws+OFF_CTX);
  int qt = blockIdx.x, h = blockIdx.y, b = blockIdx.z;
  int bh = b*8+h;
  int tid = threadIdx.x, lane = tid&63, wave = tid>>6, g = lane>>4, l15 = lane&15;
  __shared__ bf16 Ks[32*64];
  __shared__ bf16 Vs[64*32];
  __shared__ bf16 Ps[4][16*32];
  const bf16* Qw = Q + ((long)bh*1024 + qt*64 + wave*16)*64;
  bf16x8 qf[2];
  qf[0] = *(const bf16x8*)(Qw + l15*64 + g*8);
  qf[1] = *(const bf16x8*)(Qw + l15*64 + 32 + g*8);
  const bf16* Kb = K + (long)bh*65536;
  const bf16* Vb = V + (long)bh*65536;
  float mr[4] = {-1e30f,-1e30f,-1e30f,-1e30f};
  float lr[4] = {0,0,0,0};
  f32x4 cacc[4] = {};
  for (int kv0 = 0; kv0 < 1024; kv0 += 32) {
    __syncthreads();
    {
      int c = tid, row = c>>3, slot = c&7;
      gload16(Kb + (long)(kv0+row)*64 + 8*(slot^(row&7)), Ks + (long)(c-lane)*8);
      int d = c>>2, s2 = c&3;
      gload16(Vb + (long)d*1024 + kv0 + 8*(s2^((d>>1)&3)), Vs + (long)(c-lane)*8);
    }
    __syncthreads();
    f32x4 s[2] = {};
    #pragma unroll
    for (int sn=0; sn<2; ++sn) {
      int row = sn*16 + l15;
      #pragma unroll
      for (int ks2=0; ks2<2; ++ks2) {
        bf16x8 kf = *(const bf16x8*)&Ks[row*64 + 8*((4*ks2+g)^(row&7))];
        s[sn] = __builtin_amdgcn_mfma_f32_16x16x32_bf16(qf[ks2], kf, s[sn], 0,0,0);
      }
    }
    float pv[2][4];
    #pragma unroll
    for (int r=0;r<4;++r) {
      float x = fmaxf(s[0][r], s[1][r]);
      x = fmaxf(x, __shfl_xor(x, 1));
      x = fmaxf(x, __shfl_xor(x, 2));
      x = fmaxf(x, __shfl_xor(x, 4));
      x = fmaxf(x, __shfl_xor(x, 8));
      float mn = fmaxf(mr[r], x);
      float al = __expf(mr[r]-mn);
      pv[0][r] = __expf(s[0][r]-mn);
      pv[1][r] = __expf(s[1][r]-mn);
      float sum = pv[0][r]+pv[1][r];
      sum += __shfl_xor(sum, 1);
      sum += __shfl_xor(sum, 2);
      sum += __shfl_xor(sum, 4);
      sum += __shfl_xor(sum, 8);
      lr[r] = lr[r]*al + sum;
      mr[r] = mn;
      #pragma unroll
      for (int nt=0;nt<4;++nt) cacc[nt][r] *= al;
    }
    bf16* Pw = Ps[wave];
    #pragma unroll
    for (int sn=0; sn<2; ++sn)
      #pragma unroll
      for (int r=0;r<4;++r) {
        int q = 4*g + r, kv = sn*16 + l15;
        Pw[q*32 + (kv ^ (8*((q>>1)&3)))] = (bf16)pv[sn][r];
      }
    bf16x8 pa = *(const bf16x8*)&Pw[l15*32 + 8*(g ^ ((l15>>1)&3))];
    #pragma unroll
    for (int nt=0;nt<4;++nt) {
      int d = nt*16 + l15;
      bf16x8 vf = *(const bf16x8*)&Vs[d*32 + 8*(g ^ ((d>>1)&3))];
      cacc[nt] = __builtin_amdgcn_mfma_f32_16x16x32_bf16(pa, vf, cacc[nt], 0,0,0);
    }
  }
  #pragma unroll
  for (int nt=0;nt<4;++nt)
    #pragma unroll
    for (int r=0;r<4;++r) {
      int q = qt*64 + wave*16 + 4*g + r;
      int cc = h*64 + nt*16 + l15;
      ctx[((long)(b*1024+q))*512 + cc] = (bf16)(cacc[nt][r] / lr[r]);
    }
}

// ---------------- gate1 tap-partial reduce + bias + relu ----------------
__global__ __launch_bounds__(256) void k_g1red(KParams p)
{
  long o = (long)blockIdx.x*256 + threadIdx.x;   // [b][m][n], 262144
  const float* part = (const float*)(p.ws+OFF_G1P);
  int m = (int)((o >> 10) & 31);
  float a = p.gb1[m];
  #pragma unroll
  for (int t=0;t<9;++t) a += part[(long)t*262144 + o];
  ((float*)(p.ws+OFF_Y1))[o] = fmaxf(a, 0.f);
}

// ---------------- gate2 + sigmoid + sum -> gsum[b][p] ----------------
__global__ __launch_bounds__(256)
void k_g2(KParams p, const float* gw2, const float* gb2)
{
  __shared__ float st[3*32*32];
  __shared__ float sg[2][32];
  int h = blockIdx.x, b = blockIdx.y;
  const float* y1 = (const float*)(p.ws+OFF_Y1) + (long)b*32768;
  int tid = threadIdx.x;
  for (int c = tid; c < 768; c += 256) {
    int e = c*4;
    int hr = e>>10, hid = (e>>5)&31, w = e&31;
    int hh = h + hr - 1;
    float4 v = {0,0,0,0};
    if ((unsigned)hh < 32u) v = *(const float4*)(y1 + hid*1024 + hh*32 + w);
    *(float4*)&st[e] = v;
  }
  __syncthreads();
  if (tid < 64) {
    int gg = tid>>5, w = tid&31;
    float acc = gb2[gg];
    for (int hid=0; hid<32; ++hid) {
      #pragma unroll
      for (int u=0;u<3;++u) {
        #pragma unroll
        for (int v=0;v<3;++v) {
          int ww = w + v - 1;
          if ((unsigned)ww < 32u)
            acc += st[(u*32+hid)*32 + ww] * gw2[((gg*32+hid)*3+u)*3+v];
        }
      }
    }
    sg[gg][w] = 1.f/(1.f+__expf(-acc));
  }
  __syncthreads();
  if (tid < 32) ((float*)(p.ws+OFF_GSUM))[b*1024 + h*32 + tid] = sg[0][tid]+sg[1][tid];
}

// ---------------- dynamic 5x5 depthwise conv + gated fuse -> fused2[b][p][c] ----------------
__global__ __launch_bounds__(512)
void k_dyn(KParams p)
{
  int h = blockIdx.x, b = blockIdx.y;
  int c = threadIdx.x;
  const bf16* ff = (const bf16*)(p.ws+OFF_FF) + ((long)(b*512+c))*1024;
  const float* kwp = (const float*)(p.ws+OFF_KW) + b*32;
  const float* gs = (const float*)(p.ws+OFF_GSUM) + b*1024 + h*32;
  const float* vip = p.vi + ((long)(b*512+c))*1024 + h*32;
  const float* irp = p.ir + ((long)(b*512+c))*1024 + h*32;
  bf16* f2 = (bf16*)(p.ws+OFF_F2) + ((long)b*1024 + (long)h*32)*512 + c;
  float kk[25];
  #pragma unroll
  for (int j=0;j<25;++j) kk[j] = kwp[j];
  float win[5][5];
  #pragma unroll
  for (int u=0;u<5;++u) {
    int hh = h+u-2;
    #pragma unroll
    for (int v=0;v<5;++v) {
      int ww = v-2;
      win[u][v] = ((unsigned)hh<32u && (unsigned)ww<32u) ? (float)ff[hh*32+ww] : 0.f;
    }
  }
  for (int w=0; w<32; ++w) {
    float dyn = 0.f;
    #pragma unroll
    for (int u=0;u<5;++u)
      #pragma unroll
      for (int v=0;v<5;++v) dyn += win[u][v]*kk[u*5+v];
    float val = gs[w]*dyn + vip[w] + irp[w];
    f2[(long)w*512] = (bf16)val;
    #pragma unroll
    for (int u=0;u<5;++u) {
      #pragma unroll
      for (int v=0;v<4;++v) win[u][v]=win[u][v+1];
      int hh = h+u-2, ww = w+3;
      win[u][4] = ((unsigned)hh<32u && ww<32) ? (float)ff[hh*32+ww] : 0.f;
    }
  }
}

extern "C" void kernel_launch(void* const* d_in, const int* in_sizes, int n_in,
                              void* d_out, int out_size, void* d_ws, size_t ws_size,
                              hipStream_t stream)
{
  char* ws = (char*)d_ws;
  KParams p;
  p.vi = (const float*)d_in[0];  p.ir = (const float*)d_in[1];
  p.bq = (const float*)d_in[7];  p.bk = (const float*)d_in[9];
  p.bv = (const float*)d_in[11]; p.bo = (const float*)d_in[13];
  p.gb1 = (const float*)d_in[15];
  p.ws = ws; p.out = (float*)d_out;

  k_wprep<<<14467,256,0,stream>>>((const float*)d_in[6],(const float*)d_in[8],(const float*)d_in[10],(const float*)d_in[12],
      (const float*)d_in[18],(const float*)d_in[14],(const float*)d_in[19],(const float*)d_in[20],(const float*)d_in[21],
      (const float*)d_in[22],(const float*)d_in[23],
      (bf16*)(ws+OFF_WBF),(bf16*)(ws+OFF_ENHW),(bf16*)(ws+OFF_GW1R),(float*)(ws+OFF_CHS),(float*)(ws+OFF_ZP));
  k_cat<<<dim3(8,32,8),256,0,stream>>>(p.vi, p.ir, (bf16*)(ws+OFF_CATSEQ));
  k_pool<<<4096,256,0,stream>>>(p.vi,p.ir,(float*)(ws+OFF_POOL));
  k_mlp1<<<64,256,0,stream>>>((const float*)(ws+OFF_POOL),(const float*)d_in[2],(const float*)d_in[3],(float*)(ws+OFF_HID));
  k_mlp2<<<8,256,0,stream>>>((const float*)(ws+OFF_HID),(const float*)d_in[4],(const float*)d_in[5],(float*)(ws+OFF_KW));
  k_gemm<0,128,128,2,16><<<dim3(8,4,24),256,0,stream>>>(p);
  k_attn<<<dim3(16,8,8),256,0,stream>>>(p);
  k_gemm<1,128,128,2,16><<<dim3(8,4,8),256,0,stream>>>(p);
  k_gemm<3,32,256,1,32><<<dim3(4,1,72),256,0,stream>>>(p);
  k_g1red<<<1024,256,0,stream>>>(p);
  k_g2<<<dim3(32,8),256,0,stream>>>(p,(const float*)d_in[16],(const float*)d_in[17]);
  k_dyn<<<dim3(32,8),512,0,stream>>>(p);
  k_gemm<2,128,128,2,144><<<dim3(8,4,8),256,0,stream>>>(p);
}

// Round 2
// 435.258 us; speedup vs baseline: 1.7581x; 1.7581x over previous
//
#include <hip/hip_runtime.h>
#include <math.h>

typedef __bf16 bf16;
typedef __attribute__((ext_vector_type(8))) __bf16 bf16x8;
typedef __attribute__((ext_vector_type(4))) float f32x4;

// ---------------- workspace layout (bytes) ----------------
constexpr size_t OFF_CATSEQ = 0;          // 8*1024*1024*2 = 16777216  [b][p][c(0:512 vi,512:1024 ir)] bf16
constexpr size_t OFF_WBF    = 16777216;   // 4*262144*2               Wq,Wk,Wv,Wo bf16 [co][c]
constexpr size_t OFF_ENHW   = 18874368;   // 9*262144*2               enh_w repacked [t][co][ci] bf16
constexpr size_t OFF_GW1R   = 23592960;   // 9*32768*2                gate_w1 repacked [t][hid][ci] bf16
constexpr size_t OFF_CHS    = 24182784;   // 512*2*4                  bn scale[512], shift[512]
constexpr size_t OFF_ZP     = 24186880;   // 256                      zero page
constexpr size_t OFF_POOL   = 24187136;   // 8*512*4
constexpr size_t OFF_HID    = 24203520;   // 8*2048*4
constexpr size_t OFF_KW     = 24269056;   // 8*32*4
constexpr size_t OFF_Q      = 24270080;   // 8388608  [b][h][p][d] bf16 (x0.125)
constexpr size_t OFF_K      = 32658688;   // 8388608  [b][h][p][d] bf16
constexpr size_t OFF_VT     = 41047296;   // 8388608  [b][h][d][p] bf16
constexpr size_t OFF_CTX    = 49435904;   // 8388608  [b][p][c] bf16
constexpr size_t OFF_FF     = 57824512;   // 8388608  fused_feat [b][c][p] bf16
constexpr size_t OFF_G1P    = 66213120;   // 9437184  gate1 partials [t][b][32][1024] f32
constexpr size_t OFF_Y1     = 75650304;   // 1048576  y1 [b][32][1024] f32
constexpr size_t OFF_GSUM   = 76698880;   // 32768    [b][p] f32
constexpr size_t OFF_F2     = 76731648;   // 8388608  fused2 [b][p][c] bf16
// total 85120256 bytes

struct KParams {
  const float *vi, *ir, *bq, *bk, *bv, *bo, *gb1;
  char* ws;
  float* out;
};

__device__ __forceinline__ void gload16(const void* g, void* l) {
  __builtin_amdgcn_global_load_lds(
      (const __attribute__((address_space(1))) unsigned int*)g,
      (__attribute__((address_space(3))) unsigned int*)l, 16, 0, 0);
}

// ---------------- weight prep: casts, repacks, bn-fold, zero page ----------------
__global__ void k_wprep(const float* Wq, const float* Wk, const float* Wv, const float* Wo,
                        const float* enh_w, const float* gw1,
                        const float* enh_b, const float* gamma, const float* beta,
                        const float* mean, const float* var,
                        bf16* wbf, bf16* enhw, bf16* gw1r, float* chs, float* zp)
{
  long i = (long)blockIdx.x*256 + threadIdx.x;
  if (i < 1048576) {
    int which = (int)(i >> 18); long r = i & 262143;
    const float* s = which==0?Wq: which==1?Wk: which==2?Wv:Wo;
    wbf[i] = (bf16)s[r];
  } else if (i < 1048576+2359296) {
    long j = i - 1048576; long t = j/262144; long r = j%262144;   // r = co*512+ci
    enhw[j] = (bf16)enh_w[r*9 + t];
  } else if (i < 1048576+2359296+294912) {
    long j = i - (1048576+2359296); long t = j/32768; long r = j%32768; // r = hid*1024+ci
    gw1r[j] = (bf16)gw1[r*9 + t];
  } else if (i < 1048576+2359296+294912+512) {
    int c = (int)(i - (1048576+2359296+294912));
    float sc = gamma[c]*rsqrtf(var[c]+1e-5f);
    chs[c] = sc; chs[512+c] = (enh_b[c]-mean[c])*sc + beta[c];
  } else if (i < 1048576+2359296+294912+512+64) {
    zp[i - (1048576+2359296+294912+512)] = 0.f;
  }
}

// ---------------- transpose-cast vi/ir -> catseq[b][p][1024] bf16 ----------------
__global__ __launch_bounds__(256) void k_cat(const float* vi, const float* ir, bf16* cat)
{
  __shared__ float ld[32][129];
  int pt = blockIdx.x, ct = blockIdx.y, b = blockIdx.z;
  const float* src = (ct < 16) ? vi : ir;
  int c0 = (ct & 15) * 32;
  int tid = threadIdx.x;
  int p0 = pt * 128;
  for (int it = 0; it < 4; ++it) {
    int row = it*8 + (tid>>5);
    int pc  = (tid & 31) * 4;
    float4 v = *(const float4*)(src + ((long)(b*512 + c0 + row))*1024 + p0 + pc);
    ld[row][pc+0]=v.x; ld[row][pc+1]=v.y; ld[row][pc+2]=v.z; ld[row][pc+3]=v.w;
  }
  __syncthreads();
  int p = tid >> 1, half = tid & 1;
  bf16x8 o0, o1;
  #pragma unroll
  for (int j = 0; j < 8; ++j) o0[j] = (bf16)ld[half*16 + j][p];
  #pragma unroll
  for (int j = 0; j < 8; ++j) o1[j] = (bf16)ld[half*16 + 8 + j][p];
  long ccol = (ct<16 ? 0 : 512) + c0 + half*16;
  bf16* dst = cat + ((long)(b*1024 + p0 + p))*1024 + ccol;
  *(bf16x8*)dst       = o0;
  *((bf16x8*)dst + 1) = o1;
}

// ---------------- pooled[b][c] ----------------
__global__ __launch_bounds__(256) void k_pool(const float* vi, const float* ir, float* pooled)
{
  int bc = blockIdx.x;
  int tid = threadIdx.x;
  float4 a = ((const float4*)(vi + (long)bc*1024))[tid];
  float4 c = ((const float4*)(ir + (long)bc*1024))[tid];
  float s = a.x+a.y+a.z+a.w + c.x+c.y+c.z+c.w;
  #pragma unroll
  for (int off=32; off; off>>=1) s += __shfl_down(s, off);
  __shared__ float wsum[4];
  if ((tid&63)==0) wsum[tid>>6] = s;
  __syncthreads();
  if (tid==0) pooled[bc] = (wsum[0]+wsum[1]+wsum[2]+wsum[3]) * (1.f/1024.f);
}

// ---------------- mlp1: hid = relu(pooled @ w1^T + b1) ----------------
__global__ __launch_bounds__(256) void k_mlp1(const float* pooled, const float* w1, const float* b1, float* hid)
{
  __shared__ float pl[512];
  int blk = blockIdx.x; int b = blk >> 3, ch = blk & 7;
  int tid = threadIdx.x;
  ((float2*)pl)[tid] = ((const float2*)(pooled + b*512))[tid];
  __syncthreads();
  int i = ch*256 + tid;
  const float* wr = w1 + (long)i*512;
  float acc = b1[i];
  #pragma unroll 8
  for (int c = 0; c < 512; ++c) acc += pl[c]*wr[c];
  hid[b*2048 + i] = fmaxf(acc, 0.f);
}

// ---------------- mlp2 + softmax -> kw[b][25] ----------------
__global__ __launch_bounds__(256) void k_mlp2(const float* hid, const float* w2, const float* b2, float* kw)
{
  __shared__ float hd[2048];
  __shared__ float lg[32];
  int b = blockIdx.x, tid = threadIdx.x, lane = tid&63, wave = tid>>6;
  ((float2*)hd)[tid]     = ((const float2*)(hid + b*2048))[tid];
  ((float2*)hd)[tid+256] = ((const float2*)(hid + b*2048))[tid+256];
  __syncthreads();
  for (int j = wave; j < 25; j += 4) {
    const float* wr = w2 + (long)j*2048;
    float acc = 0;
    for (int i = lane; i < 2048; i += 64) acc += hd[i]*wr[i];
    #pragma unroll
    for (int off=32; off; off>>=1) acc += __shfl_down(acc, off);
    if (lane==0) lg[j] = acc + b2[j];
  }
  __syncthreads();
  if (tid==0) {
    float mx = lg[0];
    for (int j=1;j<25;++j) mx = fmaxf(mx, lg[j]);
    float s = 0.f; float e[25];
    for (int j=0;j<25;++j){ e[j]=__expf(lg[j]-mx); s+=e[j]; }
    float inv = 1.f/s;
    for (int j=0;j<25;++j) kw[b*32+j] = e[j]*inv;
  }
}

// ---------------- generic TN bf16 MFMA GEMM ----------------
// OP 0: QKV   (z = b*3+which)  D[co][p] -> Q/K p-major, V d-major
// OP 1: Wo    (z = b)          D[co][p] -> fused_feat bf16
// OP 2: enh   (z = b)          conv-as-GEMM 9 taps, BN+SiLU -> out f32
// OP 3: gate1 (z = tap*8+b)    tap partial -> g1part f32
template<int OP, int BM, int BN, int WAVES_M, int KSTEPS>
__global__ __launch_bounds__(256)
void k_gemm(KParams p)
{
  constexpr int WAVES_N = 4/WAVES_M;
  constexpr int MT = BM/(WAVES_M*16);
  constexpr int NT = BN/(WAVES_N*16);
  __shared__ bf16 As[BM*32];
  __shared__ bf16 Bs[BN*32];
  const int tid = threadIdx.x, lane = tid&63, wave = tid>>6;
  const int g = lane>>4, l15 = lane&15;
  const int wm = wave % WAVES_M, wn = wave / WAVES_M;

  int b, which = 0, tap = 0, m0, n0;
  const bf16 *Aptr, *Bptr;
  long ldb, lda;
  if constexpr (OP==0) {
    b = blockIdx.z/3; which = blockIdx.z%3;
    m0 = blockIdx.y*BM; n0 = blockIdx.x*BN;
    Aptr = (const bf16*)(p.ws+OFF_WBF) + (long)which*262144;
    Bptr = (const bf16*)(p.ws+OFF_CATSEQ) + (long)b*1048576 + (which?512:0);
    ldb = 1024; lda = 512;
  } else if constexpr (OP==1) {
    b = blockIdx.z; m0 = blockIdx.y*BM; n0 = blockIdx.x*BN;
    Aptr = (const bf16*)(p.ws+OFF_WBF) + 3L*262144;
    Bptr = (const bf16*)(p.ws+OFF_CTX) + (long)b*524288;
    ldb = 512; lda = 512;
  } else if constexpr (OP==2) {
    b = blockIdx.z; m0 = blockIdx.y*BM; n0 = blockIdx.x*BN;
    Aptr = (const bf16*)(p.ws+OFF_ENHW);
    Bptr = (const bf16*)(p.ws+OFF_F2) + (long)b*524288;
    ldb = 512; lda = 512;
  } else {
    tap = blockIdx.z>>3; b = blockIdx.z&7;
    m0 = 0; n0 = blockIdx.x*BN;
    Aptr = (const bf16*)(p.ws+OFF_GW1R) + (long)tap*32768;
    Bptr = (const bf16*)(p.ws+OFF_CATSEQ) + (long)b*1048576;
    ldb = 1024; lda = 1024;
  }
  const bf16* zp = (const bf16*)(p.ws+OFF_ZP);

  f32x4 acc[MT][NT] = {};

  for (int ks = 0; ks < KSTEPS; ++ks) {
    int t, kc;
    if constexpr (OP==2) { t = ks/16; kc = ks%16; }
    else if constexpr (OP==3) { t = tap; kc = ks; }
    else { t = 0; kc = ks; }
    __syncthreads();
    // stage A (16B chunks, src-side XOR swizzle so frag ds_read_b128 is ~2-way)
    for (int c = tid; c < BM*4; c += 256) {
      int row = c>>2, slot = c&3;
      int ss = slot ^ ((row>>1)&3);
      const bf16* src;
      if constexpr (OP==2) src = Aptr + (long)t*262144 + (long)(m0+row)*lda + kc*32 + ss*8;
      else                 src = Aptr + (long)(m0+row)*lda + kc*32 + ss*8;
      gload16(src, As + (long)(c-lane)*8);
    }
    // stage B (with tap shift + border mask for conv ops)
    for (int c = tid; c < BN*4; c += 256) {
      int row = c>>2, slot = c&3;
      int ss = slot ^ ((row>>1)&3);
      const bf16* src;
      if constexpr (OP==2 || OP==3) {
        int pp = n0 + row;
        int hh = (pp>>5) + t/3 - 1, ww = (pp&31) + t%3 - 1;
        bool valid = ((unsigned)hh < 32u) && ((unsigned)ww < 32u);
        src = valid ? (Bptr + (long)(hh*32+ww)*ldb + kc*32 + ss*8) : zp;
      } else {
        src = Bptr + (long)(n0+row)*ldb + kc*32 + ss*8;
      }
      gload16(src, Bs + (long)(c-lane)*8);
    }
    __syncthreads();
    bf16x8 af[MT], bq_[NT];
    #pragma unroll
    for (int mt=0; mt<MT; ++mt) {
      int row = wm*MT*16 + mt*16 + l15;
      af[mt] = *(const bf16x8*)&As[row*32 + 8*(g ^ ((row>>1)&3))];
    }
    #pragma unroll
    for (int nt=0; nt<NT; ++nt) {
      int row = wn*NT*16 + nt*16 + l15;
      bq_[nt] = *(const bf16x8*)&Bs[row*32 + 8*(g ^ ((row>>1)&3))];
    }
    #pragma unroll
    for (int mt=0; mt<MT; ++mt)
      #pragma unroll
      for (int nt=0; nt<NT; ++nt)
        acc[mt][nt] = __builtin_amdgcn_mfma_f32_16x16x32_bf16(af[mt], bq_[nt], acc[mt][nt], 0,0,0);
  }

  // epilogue (D: row m = 4*(lane>>4)+reg, col n = lane&15)
  #pragma unroll
  for (int mt=0; mt<MT; ++mt) {
    #pragma unroll
    for (int nt=0; nt<NT; ++nt) {
      #pragma unroll
      for (int reg=0; reg<4; ++reg) {
        int m = m0 + wm*MT*16 + mt*16 + 4*g + reg;
        int n = n0 + wn*NT*16 + nt*16 + l15;
        float v = acc[mt][nt][reg];
        if constexpr (OP==0) {
          const float* bias = which==0?p.bq: which==1?p.bk:p.bv;
          v += bias[m];
          if (which==0) v *= 0.125f;
          int h = m>>6, d = m&63;
          if (which==2) ((bf16*)(p.ws+OFF_VT))[((long)(b*8+h)*64 + d)*1024 + n] = (bf16)v;
          else {
            bf16* dst = (bf16*)(p.ws + (which==0?OFF_Q:OFF_K));
            dst[((long)(b*8+h)*1024 + n)*64 + d] = (bf16)v;
          }
        } else if constexpr (OP==1) {
          v += p.bo[m];
          ((bf16*)(p.ws+OFF_FF))[((long)(b*512+m))*1024 + n] = (bf16)v;
        } else if constexpr (OP==2) {
          const float* chs = (const float*)(p.ws+OFF_CHS);
          float yn = v*chs[m] + chs[512+m];
          p.out[((long)(b*512+m))*1024 + n] = yn * (1.f/(1.f+__expf(-yn)));
        } else {
          ((float*)(p.ws+OFF_G1P))[((long)((tap*8+b)*32+m))*1024 + n] = v;
        }
      }
    }
  }
}

// ---------------- flash attention ----------------
__global__ __launch_bounds__(256)
void k_attn(KParams p)
{
  const bf16* Q = (const bf16*)(p.ws+OFF_Q);
  const bf16* K = (const bf16*)(p.ws+OFF_K);
  const bf16* V = (const bf16*)(p.ws+OFF_VT);
  bf16* ctx = (bf16*)(p.ws+OFF_CTX);
  int qt = blockIdx.x, h = blockIdx.y, b = blockIdx.z;
  int bh = b*8+h;
  int tid = threadIdx.x, lane = tid&63, wave = tid>>6, g = lane>>4, l15 = lane&15;
  __shared__ bf16 Ks[32*64];
  __shared__ bf16 Vs[64*32];
  __shared__ bf16 Ps[4][16*32];
  const bf16* Qw = Q + ((long)bh*1024 + qt*64 + wave*16)*64;
  bf16x8 qf[2];
  qf[0] = *(const bf16x8*)(Qw + l15*64 + g*8);
  qf[1] = *(const bf16x8*)(Qw + l15*64 + 32 + g*8);
  const bf16* Kb = K + (long)bh*65536;
  const bf16* Vb = V + (long)bh*65536;
  float mr[4] = {-1e30f,-1e30f,-1e30f,-1e30f};
  float lr[4] = {0,0,0,0};
  f32x4 cacc[4] = {};
  for (int kv0 = 0; kv0 < 1024; kv0 += 32) {
    __syncthreads();
    {
      int c = tid, row = c>>3, slot = c&7;
      gload16(Kb + (long)(kv0+row)*64 + 8*(slot^(row&7)), Ks + (long)(c-lane)*8);
      int d = c>>2, s2 = c&3;
      gload16(Vb + (long)d*1024 + kv0 + 8*(s2^((d>>1)&3)), Vs + (long)(c-lane)*8);
    }
    __syncthreads();
    f32x4 s[2] = {};
    #pragma unroll
    for (int sn=0; sn<2; ++sn) {
      int row = sn*16 + l15;
      #pragma unroll
      for (int ks2=0; ks2<2; ++ks2) {
        bf16x8 kf = *(const bf16x8*)&Ks[row*64 + 8*((4*ks2+g)^(row&7))];
        s[sn] = __builtin_amdgcn_mfma_f32_16x16x32_bf16(qf[ks2], kf, s[sn], 0,0,0);
      }
    }
    float pv[2][4];
    #pragma unroll
    for (int r=0;r<4;++r) {
      float x = fmaxf(s[0][r], s[1][r]);
      x = fmaxf(x, __shfl_xor(x, 1));
      x = fmaxf(x, __shfl_xor(x, 2));
      x = fmaxf(x, __shfl_xor(x, 4));
      x = fmaxf(x, __shfl_xor(x, 8));
      float mn = fmaxf(mr[r], x);
      float al = __expf(mr[r]-mn);
      pv[0][r] = __expf(s[0][r]-mn);
      pv[1][r] = __expf(s[1][r]-mn);
      float sum = pv[0][r]+pv[1][r];
      sum += __shfl_xor(sum, 1);
      sum += __shfl_xor(sum, 2);
      sum += __shfl_xor(sum, 4);
      sum += __shfl_xor(sum, 8);
      lr[r] = lr[r]*al + sum;
      mr[r] = mn;
      #pragma unroll
      for (int nt=0;nt<4;++nt) cacc[nt][r] *= al;
    }
    bf16* Pw = Ps[wave];
    #pragma unroll
    for (int sn=0; sn<2; ++sn)
      #pragma unroll
      for (int r=0;r<4;++r) {
        int q = 4*g + r, kv = sn*16 + l15;
        Pw[q*32 + (kv ^ (8*((q>>1)&3)))] = (bf16)pv[sn][r];
      }
    bf16x8 pa = *(const bf16x8*)&Pw[l15*32 + 8*(g ^ ((l15>>1)&3))];
    #pragma unroll
    for (int nt=0;nt<4;++nt) {
      int d = nt*16 + l15;
      bf16x8 vf = *(const bf16x8*)&Vs[d*32 + 8*(g ^ ((d>>1)&3))];
      cacc[nt] = __builtin_amdgcn_mfma_f32_16x16x32_bf16(pa, vf, cacc[nt], 0,0,0);
    }
  }
  #pragma unroll
  for (int nt=0;nt<4;++nt)
    #pragma unroll
    for (int r=0;r<4;++r) {
      int q = qt*64 + wave*16 + 4*g + r;
      int cc = h*64 + nt*16 + l15;
      ctx[((long)(b*1024+q))*512 + cc] = (bf16)(cacc[nt][r] / lr[r]);
    }
}

// ---------------- gate1 tap-partial reduce + bias + relu ----------------
__global__ __launch_bounds__(256) void k_g1red(KParams p)
{
  long o = (long)blockIdx.x*256 + threadIdx.x;   // [b][m][n], 262144
  const float* part = (const float*)(p.ws+OFF_G1P);
  int m = (int)((o >> 10) & 31);
  float a = p.gb1[m];
  #pragma unroll
  for (int t=0;t<9;++t) a += part[(long)t*262144 + o];
  ((float*)(p.ws+OFF_Y1))[o] = fmaxf(a, 0.f);
}

// ---------------- gate2 + sigmoid + sum -> gsum[b][p] ----------------
__global__ __launch_bounds__(256)
void k_g2(KParams p, const float* gw2, const float* gb2)
{
  __shared__ float st[3*32*32];
  __shared__ float sg[2][32];
  int h = blockIdx.x, b = blockIdx.y;
  const float* y1 = (const float*)(p.ws+OFF_Y1) + (long)b*32768;
  int tid = threadIdx.x;
  for (int c = tid; c < 768; c += 256) {
    int e = c*4;
    int hr = e>>10, hid = (e>>5)&31, w = e&31;
    int hh = h + hr - 1;
    float4 v = {0,0,0,0};
    if ((unsigned)hh < 32u) v = *(const float4*)(y1 + hid*1024 + hh*32 + w);
    *(float4*)&st[e] = v;
  }
  __syncthreads();
  if (tid < 64) {
    int gg = tid>>5, w = tid&31;
    float acc = gb2[gg];
    for (int hid=0; hid<32; ++hid) {
      #pragma unroll
      for (int u=0;u<3;++u) {
        #pragma unroll
        for (int v=0;v<3;++v) {
          int ww = w + v - 1;
          if ((unsigned)ww < 32u)
            acc += st[(u*32+hid)*32 + ww] * gw2[((gg*32+hid)*3+u)*3+v];
        }
      }
    }
    sg[gg][w] = 1.f/(1.f+__expf(-acc));
  }
  __syncthreads();
  if (tid < 32) ((float*)(p.ws+OFF_GSUM))[b*1024 + h*32 + tid] = sg[0][tid]+sg[1][tid];
}

// ---------------- dynamic 5x5 depthwise conv + gated fuse -> fused2[b][p][c] ----------------
// position-major rewrite: block = (ctile of 16, b); thread = (h,w); ff staged in LDS
__global__ __launch_bounds__(512)
void k_dyn(KParams p)
{
  __shared__ float ffs[16*1024];
  int ct = blockIdx.x;            // 0..31
  int b  = blockIdx.y;            // 0..7
  int c0 = ct*16;
  int t = threadIdx.x;            // 512
  const bf16* ffg = (const bf16*)(p.ws+OFF_FF) + ((long)(b*512 + c0))*1024;
  // stage ff (16 channel planes) -> f32 LDS, coalesced bf16x8 reads
  #pragma unroll
  for (int k2 = 0; k2 < 4; ++k2) {
    int chunk = t + 512*k2;
    int c = chunk >> 7, j = chunk & 127;
    bf16x8 v = *(const bf16x8*)(ffg + (long)c*1024 + j*8);
    float* d = ffs + c*1024 + j*8;
    #pragma unroll
    for (int e=0;e<8;++e) d[e] = (float)v[e];
  }
  const float* kwp = (const float*)(p.ws+OFF_KW) + b*32;
  float kk[25];
  #pragma unroll
  for (int j=0;j<25;++j) kk[j] = kwp[j];
  __syncthreads();
  int w = t & 31;
  int h0 = t >> 5;                // 0..15
  #pragma unroll
  for (int pass=0; pass<2; ++pass) {
    int h = h0 + pass*16;
    int pos = h*32 + w;
    float gsw = ((const float*)(p.ws+OFF_GSUM))[b*1024 + pos];
    const float* vip = p.vi + ((long)(b*512 + c0))*1024 + pos;
    const float* irp = p.ir + ((long)(b*512 + c0))*1024 + pos;
    bf16 outv[16];
    #pragma unroll
    for (int c=0;c<16;++c) {
      float dyn = 0.f;
      #pragma unroll
      for (int u=0;u<5;++u) {
        int hh = h+u-2;
        bool okh = (unsigned)hh < 32u;
        #pragma unroll
        for (int v=0;v<5;++v) {
          int ww = w+v-2;
          bool ok = okh && ((unsigned)ww < 32u);
          float fv = ffs[c*1024 + (hh&31)*32 + (ww&31)];
          dyn += (ok ? fv : 0.f) * kk[u*5+v];
        }
      }
      float val = gsw*dyn + vip[(long)c*1024] + irp[(long)c*1024];
      outv[c] = (bf16)val;
    }
    bf16* f2 = (bf16*)(p.ws+OFF_F2) + ((long)(b*1024 + pos))*512 + c0;
    *(bf16x8*)f2       = *(bf16x8*)&outv[0];
    *((bf16x8*)f2 + 1) = *(bf16x8*)&outv[8];
  }
}

extern "C" void kernel_launch(void* const* d_in, const int* in_sizes, int n_in,
                              void* d_out, int out_size, void* d_ws, size_t ws_size,
                              hipStream_t stream)
{
  char* ws = (char*)d_ws;
  KParams p;
  p.vi = (const float*)d_in[0];  p.ir = (const float*)d_in[1];
  p.bq = (const float*)d_in[7];  p.bk = (const float*)d_in[9];
  p.bv = (const float*)d_in[11]; p.bo = (const float*)d_in[13];
  p.gb1 = (const float*)d_in[15];
  p.ws = ws; p.out = (float*)d_out;

  k_wprep<<<14467,256,0,stream>>>((const float*)d_in[6],(const float*)d_in[8],(const float*)d_in[10],(const float*)d_in[12],
      (const float*)d_in[18],(const float*)d_in[14],(const float*)d_in[19],(const float*)d_in[20],(const float*)d_in[21],
      (const float*)d_in[22],(const float*)d_in[23],
      (bf16*)(ws+OFF_WBF),(bf16*)(ws+OFF_ENHW),(bf16*)(ws+OFF_GW1R),(float*)(ws+OFF_CHS),(float*)(ws+OFF_ZP));
  k_cat<<<dim3(8,32,8),256,0,stream>>>(p.vi, p.ir, (bf16*)(ws+OFF_CATSEQ));
  k_pool<<<4096,256,0,stream>>>(p.vi,p.ir,(float*)(ws+OFF_POOL));
  k_mlp1<<<64,256,0,stream>>>((const float*)(ws+OFF_POOL),(const float*)d_in[2],(const float*)d_in[3],(float*)(ws+OFF_HID));
  k_mlp2<<<8,256,0,stream>>>((const float*)(ws+OFF_HID),(const float*)d_in[4],(const float*)d_in[5],(float*)(ws+OFF_KW));
  k_gemm<0,128,128,2,16><<<dim3(8,4,24),256,0,stream>>>(p);
  k_attn<<<dim3(16,8,8),256,0,stream>>>(p);
  k_gemm<1,128,128,2,16><<<dim3(8,4,8),256,0,stream>>>(p);
  k_gemm<3,32,256,1,32><<<dim3(4,1,72),256,0,stream>>>(p);
  k_g1red<<<1024,256,0,stream>>>(p);
  k_g2<<<dim3(32,8),256,0,stream>>>(p,(const float*)d_in[16],(const float*)d_in[17]);
  k_dyn<<<dim3(32,8),512,0,stream>>>(p);
  k_gemm<2,128,128,2,144><<<dim3(8,4,8),256,0,stream>>>(p);
}

// Round 3
// 383.548 us; speedup vs baseline: 1.9952x; 1.1348x over previous
//
#include <hip/hip_runtime.h>
#include <math.h>

typedef __bf16 bf16;
typedef __attribute__((ext_vector_type(8))) __bf16 bf16x8;
typedef __attribute__((ext_vector_type(4))) float f32x4;

// ---------------- workspace layout (bytes) ----------------
constexpr size_t OFF_CATSEQ = 0;          // 16777216  [b][p][c(0:512 vi,512:1024 ir)] bf16
constexpr size_t OFF_WBF    = 16777216;   // 2097152   Wq,Wk,Wv,Wo bf16 [co][c]
constexpr size_t OFF_ENHW   = 18874368;   // 4718592   enh_w repacked [t][co][ci] bf16
constexpr size_t OFF_GW1R   = 23592960;   // 589824    gate_w1 repacked [t][hid][ci] bf16
constexpr size_t OFF_CHS    = 24182784;   // 4096      bn scale[512], shift[512]
constexpr size_t OFF_ZP     = 24186880;   // 256       zero page
constexpr size_t OFF_POOL   = 24187136;   // 16384
constexpr size_t OFF_HID    = 24203520;   // 65536
constexpr size_t OFF_KW     = 24269056;   // 1024
constexpr size_t OFF_Q      = 24270080;   // 8388608  [b][h][p][d] bf16 (x0.125); reused as enh partial kg=0 (f32, 16.78MB)
constexpr size_t OFF_K      = 32658688;   // 8388608  [b][h][p][d] bf16
constexpr size_t OFF_VT     = 41047296;   // 8388608  [b][h][d][p] bf16; reused as enh partial kg=1
constexpr size_t OFF_CTX    = 49435904;   // 8388608  [b][p][c] bf16
constexpr size_t OFF_FF     = 57824512;   // 8388608  fused_feat [b][c][p] bf16
constexpr size_t OFF_G1P    = 66213120;   // 9437184  gate1 partials [t][b][32][1024] f32
constexpr size_t OFF_Y1     = 75650304;   // 1048576  y1 [b][32][1024] f32
constexpr size_t OFF_GSUM   = 76698880;   // 32768    [b][p] f32
constexpr size_t OFF_F2     = 76731648;   // 8388608  fused2 [b][p][c] bf16
// total 85120256 bytes

struct KParams {
  const float *vi, *ir, *bq, *bk, *bv, *bo, *gb1;
  char* ws;
  float* out;
};

__device__ __forceinline__ void gload16(const void* g, void* l) {
  __builtin_amdgcn_global_load_lds(
      (const __attribute__((address_space(1))) unsigned int*)g,
      (__attribute__((address_space(3))) unsigned int*)l, 16, 0, 0);
}

// ---------------- weight prep: casts, repacks, bn-fold, zero page ----------------
__global__ void k_wprep(const float* Wq, const float* Wk, const float* Wv, const float* Wo,
                        const float* enh_w, const float* gw1,
                        const float* enh_b, const float* gamma, const float* beta,
                        const float* mean, const float* var,
                        bf16* wbf, bf16* enhw, bf16* gw1r, float* chs, float* zp)
{
  long i = (long)blockIdx.x*256 + threadIdx.x;
  if (i < 1048576) {
    int which = (int)(i >> 18); long r = i & 262143;
    const float* s = which==0?Wq: which==1?Wk: which==2?Wv:Wo;
    wbf[i] = (bf16)s[r];
  } else if (i < 1048576+2359296) {
    long j = i - 1048576; long t = j/262144; long r = j%262144;   // r = co*512+ci
    enhw[j] = (bf16)enh_w[r*9 + t];
  } else if (i < 1048576+2359296+294912) {
    long j = i - (1048576+2359296); long t = j/32768; long r = j%32768; // r = hid*1024+ci
    gw1r[j] = (bf16)gw1[r*9 + t];
  } else if (i < 1048576+2359296+294912+512) {
    int c = (int)(i - (1048576+2359296+294912));
    float sc = gamma[c]*rsqrtf(var[c]+1e-5f);
    chs[c] = sc; chs[512+c] = (enh_b[c]-mean[c])*sc + beta[c];
  } else if (i < 1048576+2359296+294912+512+64) {
    zp[i - (1048576+2359296+294912+512)] = 0.f;
  }
}

// ---------------- transpose-cast vi/ir -> catseq[b][p][1024] bf16 ----------------
__global__ __launch_bounds__(256) void k_cat(const float* vi, const float* ir, bf16* cat)
{
  __shared__ float ld[32][129];
  int pt = blockIdx.x, ct = blockIdx.y, b = blockIdx.z;
  const float* src = (ct < 16) ? vi : ir;
  int c0 = (ct & 15) * 32;
  int tid = threadIdx.x;
  int p0 = pt * 128;
  for (int it = 0; it < 4; ++it) {
    int row = it*8 + (tid>>5);
    int pc  = (tid & 31) * 4;
    float4 v = *(const float4*)(src + ((long)(b*512 + c0 + row))*1024 + p0 + pc);
    ld[row][pc+0]=v.x; ld[row][pc+1]=v.y; ld[row][pc+2]=v.z; ld[row][pc+3]=v.w;
  }
  __syncthreads();
  int p = tid >> 1, half = tid & 1;
  bf16x8 o0, o1;
  #pragma unroll
  for (int j = 0; j < 8; ++j) o0[j] = (bf16)ld[half*16 + j][p];
  #pragma unroll
  for (int j = 0; j < 8; ++j) o1[j] = (bf16)ld[half*16 + 8 + j][p];
  long ccol = (ct<16 ? 0 : 512) + c0 + half*16;
  bf16* dst = cat + ((long)(b*1024 + p0 + p))*1024 + ccol;
  *(bf16x8*)dst       = o0;
  *((bf16x8*)dst + 1) = o1;
}

// ---------------- pooled[b][c] ----------------
__global__ __launch_bounds__(256) void k_pool(const float* vi, const float* ir, float* pooled)
{
  int bc = blockIdx.x;
  int tid = threadIdx.x;
  float4 a = ((const float4*)(vi + (long)bc*1024))[tid];
  float4 c = ((const float4*)(ir + (long)bc*1024))[tid];
  float s = a.x+a.y+a.z+a.w + c.x+c.y+c.z+c.w;
  #pragma unroll
  for (int off=32; off; off>>=1) s += __shfl_down(s, off);
  __shared__ float wsum[4];
  if ((tid&63)==0) wsum[tid>>6] = s;
  __syncthreads();
  if (tid==0) pooled[bc] = (wsum[0]+wsum[1]+wsum[2]+wsum[3]) * (1.f/1024.f);
}

// ---------------- mlp1: hid = relu(pooled @ w1^T + b1) ----------------
__global__ __launch_bounds__(256) void k_mlp1(const float* pooled, const float* w1, const float* b1, float* hid)
{
  __shared__ float pl[512];
  int blk = blockIdx.x; int b = blk >> 3, ch = blk & 7;
  int tid = threadIdx.x;
  ((float2*)pl)[tid] = ((const float2*)(pooled + b*512))[tid];
  __syncthreads();
  int i = ch*256 + tid;
  const float* wr = w1 + (long)i*512;
  float acc = b1[i];
  #pragma unroll 8
  for (int c = 0; c < 512; ++c) acc += pl[c]*wr[c];
  hid[b*2048 + i] = fmaxf(acc, 0.f);
}

// ---------------- mlp2 + softmax -> kw[b][25] ----------------
__global__ __launch_bounds__(256) void k_mlp2(const float* hid, const float* w2, const float* b2, float* kw)
{
  __shared__ float hd[2048];
  __shared__ float lg[32];
  int b = blockIdx.x, tid = threadIdx.x, lane = tid&63, wave = tid>>6;
  ((float2*)hd)[tid]     = ((const float2*)(hid + b*2048))[tid];
  ((float2*)hd)[tid+256] = ((const float2*)(hid + b*2048))[tid+256];
  __syncthreads();
  for (int j = wave; j < 25; j += 4) {
    const float* wr = w2 + (long)j*2048;
    float acc = 0;
    for (int i = lane; i < 2048; i += 64) acc += hd[i]*wr[i];
    #pragma unroll
    for (int off=32; off; off>>=1) acc += __shfl_down(acc, off);
    if (lane==0) lg[j] = acc + b2[j];
  }
  __syncthreads();
  if (tid==0) {
    float mx = lg[0];
    for (int j=1;j<25;++j) mx = fmaxf(mx, lg[j]);
    float s = 0.f; float e[25];
    for (int j=0;j<25;++j){ e[j]=__expf(lg[j]-mx); s+=e[j]; }
    float inv = 1.f/s;
    for (int j=0;j<25;++j) kw[b*32+j] = e[j]*inv;
  }
}

// ---------------- generic TN bf16 MFMA GEMM (double-buffered 2-phase prefetch) ----------------
// OP 0: QKV   (z = b*3+which)  D[co][p] -> Q/K p-major, V d-major
// OP 1: Wo    (z = b)          D[co][p] -> fused_feat bf16
// OP 2: enh   (z = kg*8+b)     conv-as-GEMM, split-K=2 (72 steps each) -> f32 partials
// OP 3: gate1 (z = tap*8+b)    tap partial -> g1part f32
template<int OP, int BM, int BN, int WAVES_M, int KSTEPS>
__global__ __launch_bounds__(256)
void k_gemm(KParams p)
{
  constexpr int WAVES_N = 4/WAVES_M;
  constexpr int MT = BM/(WAVES_M*16);
  constexpr int NT = BN/(WAVES_N*16);
  __shared__ bf16 As[2][BM*32];
  __shared__ bf16 Bs[2][BN*32];
  const int tid = threadIdx.x, lane = tid&63, wave = tid>>6;
  const int g = lane>>4, l15 = lane&15;
  const int wm = wave % WAVES_M, wn = wave / WAVES_M;

  int b, which = 0, tap = 0, kg = 0, m0, n0;
  const bf16 *Aptr, *Bptr;
  long ldb, lda;
  if constexpr (OP==0) {
    b = blockIdx.z/3; which = blockIdx.z%3;
    m0 = blockIdx.y*BM; n0 = blockIdx.x*BN;
    Aptr = (const bf16*)(p.ws+OFF_WBF) + (long)which*262144;
    Bptr = (const bf16*)(p.ws+OFF_CATSEQ) + (long)b*1048576 + (which?512:0);
    ldb = 1024; lda = 512;
  } else if constexpr (OP==1) {
    b = blockIdx.z; m0 = blockIdx.y*BM; n0 = blockIdx.x*BN;
    Aptr = (const bf16*)(p.ws+OFF_WBF) + 3L*262144;
    Bptr = (const bf16*)(p.ws+OFF_CTX) + (long)b*524288;
    ldb = 512; lda = 512;
  } else if constexpr (OP==2) {
    kg = blockIdx.z>>3; b = blockIdx.z&7;
    m0 = blockIdx.y*BM; n0 = blockIdx.x*BN;
    Aptr = (const bf16*)(p.ws+OFF_ENHW);
    Bptr = (const bf16*)(p.ws+OFF_F2) + (long)b*524288;
    ldb = 512; lda = 512;
  } else {
    tap = blockIdx.z>>3; b = blockIdx.z&7;
    m0 = 0; n0 = blockIdx.x*BN;
    Aptr = (const bf16*)(p.ws+OFF_GW1R) + (long)tap*32768;
    Bptr = (const bf16*)(p.ws+OFF_CATSEQ) + (long)b*1048576;
    ldb = 1024; lda = 1024;
  }
  const bf16* zp = (const bf16*)(p.ws+OFF_ZP);

  // stage one K-step into buffer `buf`
  auto STAGE = [&](int buf, int ks) {
    int t, kc;
    if constexpr (OP==2) { int gks = kg*72 + ks; t = gks>>4; kc = gks&15; }
    else if constexpr (OP==3) { t = tap; kc = ks; }
    else { t = 0; kc = ks; }
    for (int c = tid; c < BM*4; c += 256) {
      int row = c>>2, slot = c&3;
      int ss = slot ^ ((row>>1)&3);
      const bf16* src;
      if constexpr (OP==2) src = Aptr + (long)t*262144 + (long)(m0+row)*lda + kc*32 + ss*8;
      else                 src = Aptr + (long)(m0+row)*lda + kc*32 + ss*8;
      gload16(src, As[buf] + (long)(c-lane)*8);
    }
    for (int c = tid; c < BN*4; c += 256) {
      int row = c>>2, slot = c&3;
      int ss = slot ^ ((row>>1)&3);
      const bf16* src;
      if constexpr (OP==2 || OP==3) {
        int pp = n0 + row;
        int hh = (pp>>5) + t/3 - 1, ww = (pp&31) + t%3 - 1;
        bool valid = ((unsigned)hh < 32u) && ((unsigned)ww < 32u);
        src = valid ? (Bptr + (long)(hh*32+ww)*ldb + kc*32 + ss*8) : zp;
      } else {
        src = Bptr + (long)(n0+row)*ldb + kc*32 + ss*8;
      }
      gload16(src, Bs[buf] + (long)(c-lane)*8);
    }
  };

  f32x4 acc[MT][NT] = {};

  STAGE(0, 0);
  __syncthreads();            // vmcnt(0)+lgkmcnt(0)+barrier: buf0 ready
  int cur = 0;
  #pragma unroll 2
  for (int ks = 0; ks < KSTEPS; ++ks) {
    if (ks+1 < KSTEPS) STAGE(cur^1, ks+1);   // next tile's loads fly under compute
    bf16x8 af[MT], bq_[NT];
    #pragma unroll
    for (int mt=0; mt<MT; ++mt) {
      int row = wm*MT*16 + mt*16 + l15;
      af[mt] = *(const bf16x8*)&As[cur][row*32 + 8*(g ^ ((row>>1)&3))];
    }
    #pragma unroll
    for (int nt=0; nt<NT; ++nt) {
      int row = wn*NT*16 + nt*16 + l15;
      bq_[nt] = *(const bf16x8*)&Bs[cur][row*32 + 8*(g ^ ((row>>1)&3))];
    }
    #pragma unroll
    for (int mt=0; mt<MT; ++mt)
      #pragma unroll
      for (int nt=0; nt<NT; ++nt)
        acc[mt][nt] = __builtin_amdgcn_mfma_f32_16x16x32_bf16(af[mt], bq_[nt], acc[mt][nt], 0,0,0);
    __syncthreads();          // drains next-tile loads + syncs buffer swap
    cur ^= 1;
  }

  // epilogue (D: row m = 4*(lane>>4)+reg, col n = lane&15)
  #pragma unroll
  for (int mt=0; mt<MT; ++mt) {
    #pragma unroll
    for (int nt=0; nt<NT; ++nt) {
      #pragma unroll
      for (int reg=0; reg<4; ++reg) {
        int m = m0 + wm*MT*16 + mt*16 + 4*g + reg;
        int n = n0 + wn*NT*16 + nt*16 + l15;
        float v = acc[mt][nt][reg];
        if constexpr (OP==0) {
          const float* bias = which==0?p.bq: which==1?p.bk:p.bv;
          v += bias[m];
          if (which==0) v *= 0.125f;
          int h = m>>6, d = m&63;
          if (which==2) ((bf16*)(p.ws+OFF_VT))[((long)(b*8+h)*64 + d)*1024 + n] = (bf16)v;
          else {
            bf16* dst = (bf16*)(p.ws + (which==0?OFF_Q:OFF_K));
            dst[((long)(b*8+h)*1024 + n)*64 + d] = (bf16)v;
          }
        } else if constexpr (OP==1) {
          v += p.bo[m];
          ((bf16*)(p.ws+OFF_FF))[((long)(b*512+m))*1024 + n] = (bf16)v;
        } else if constexpr (OP==2) {
          float* part = (float*)(p.ws+OFF_Q) + (long)kg*4194304;
          part[((long)b*512+m)*1024 + n] = v;
        } else {
          ((float*)(p.ws+OFF_G1P))[((long)((tap*8+b)*32+m))*1024 + n] = v;
        }
      }
    }
  }
}

// ---------------- enh split-K reduce + BN + SiLU -> out ----------------
__global__ __launch_bounds__(256) void k_enhred(KParams p)
{
  long e = ((long)blockIdx.x*256 + threadIdx.x)*4;
  const float* part = (const float*)(p.ws+OFF_Q);
  float4 a = *(const float4*)(part + e);
  float4 c = *(const float4*)(part + 4194304 + e);
  int m = (int)((e>>10)&511);
  const float* chs = (const float*)(p.ws+OFF_CHS);
  float sc = chs[m], sh = chs[512+m];
  float4 o;
  float y0 = (a.x+c.x)*sc+sh, y1 = (a.y+c.y)*sc+sh, y2 = (a.z+c.z)*sc+sh, y3 = (a.w+c.w)*sc+sh;
  o.x = y0/(1.f+__expf(-y0)); o.y = y1/(1.f+__expf(-y1));
  o.z = y2/(1.f+__expf(-y2)); o.w = y3/(1.f+__expf(-y3));
  *(float4*)(p.out + e) = o;
}

// ---------------- flash attention ----------------
__global__ __launch_bounds__(256)
void k_attn(KParams p)
{
  const bf16* Q = (const bf16*)(p.ws+OFF_Q);
  const bf16* K = (const bf16*)(p.ws+OFF_K);
  const bf16* V = (const bf16*)(p.ws+OFF_VT);
  bf16* ctx = (bf16*)(p.ws+OFF_CTX);
  int qt = blockIdx.x, h = blockIdx.y, b = blockIdx.z;
  int bh = b*8+h;
  int tid = threadIdx.x, lane = tid&63, wave = tid>>6, g = lane>>4, l15 = lane&15;
  __shared__ bf16 Ks[32*64];
  __shared__ bf16 Vs[64*32];
  __shared__ bf16 Ps[4][16*32];
  const bf16* Qw = Q + ((long)bh*1024 + qt*64 + wave*16)*64;
  bf16x8 qf[2];
  qf[0] = *(const bf16x8*)(Qw + l15*64 + g*8);
  qf[1] = *(const bf16x8*)(Qw + l15*64 + 32 + g*8);
  const bf16* Kb = K + (long)bh*65536;
  const bf16* Vb = V + (long)bh*65536;
  float mr[4] = {-1e30f,-1e30f,-1e30f,-1e30f};
  float lr[4] = {0,0,0,0};
  f32x4 cacc[4] = {};
  for (int kv0 = 0; kv0 < 1024; kv0 += 32) {
    __syncthreads();
    {
      int c = tid, row = c>>3, slot = c&7;
      gload16(Kb + (long)(kv0+row)*64 + 8*(slot^(row&7)), Ks + (long)(c-lane)*8);
      int d = c>>2, s2 = c&3;
      gload16(Vb + (long)d*1024 + kv0 + 8*(s2^((d>>1)&3)), Vs + (long)(c-lane)*8);
    }
    __syncthreads();
    f32x4 s[2] = {};
    #pragma unroll
    for (int sn=0; sn<2; ++sn) {
      int row = sn*16 + l15;
      #pragma unroll
      for (int ks2=0; ks2<2; ++ks2) {
        bf16x8 kf = *(const bf16x8*)&Ks[row*64 + 8*((4*ks2+g)^(row&7))];
        s[sn] = __builtin_amdgcn_mfma_f32_16x16x32_bf16(qf[ks2], kf, s[sn], 0,0,0);
      }
    }
    float pv[2][4];
    #pragma unroll
    for (int r=0;r<4;++r) {
      float x = fmaxf(s[0][r], s[1][r]);
      x = fmaxf(x, __shfl_xor(x, 1));
      x = fmaxf(x, __shfl_xor(x, 2));
      x = fmaxf(x, __shfl_xor(x, 4));
      x = fmaxf(x, __shfl_xor(x, 8));
      float mn = fmaxf(mr[r], x);
      float al = __expf(mr[r]-mn);
      pv[0][r] = __expf(s[0][r]-mn);
      pv[1][r] = __expf(s[1][r]-mn);
      float sum = pv[0][r]+pv[1][r];
      sum += __shfl_xor(sum, 1);
      sum += __shfl_xor(sum, 2);
      sum += __shfl_xor(sum, 4);
      sum += __shfl_xor(sum, 8);
      lr[r] = lr[r]*al + sum;
      mr[r] = mn;
      #pragma unroll
      for (int nt=0;nt<4;++nt) cacc[nt][r] *= al;
    }
    bf16* Pw = Ps[wave];
    #pragma unroll
    for (int sn=0; sn<2; ++sn)
      #pragma unroll
      for (int r=0;r<4;++r) {
        int q = 4*g + r, kv = sn*16 + l15;
        Pw[q*32 + (kv ^ (8*((q>>1)&3)))] = (bf16)pv[sn][r];
      }
    bf16x8 pa = *(const bf16x8*)&Pw[l15*32 + 8*(g ^ ((l15>>1)&3))];
    #pragma unroll
    for (int nt=0;nt<4;++nt) {
      int d = nt*16 + l15;
      bf16x8 vf = *(const bf16x8*)&Vs[d*32 + 8*(g ^ ((d>>1)&3))];
      cacc[nt] = __builtin_amdgcn_mfma_f32_16x16x32_bf16(pa, vf, cacc[nt], 0,0,0);
    }
  }
  #pragma unroll
  for (int nt=0;nt<4;++nt)
    #pragma unroll
    for (int r=0;r<4;++r) {
      int q = qt*64 + wave*16 + 4*g + r;
      int cc = h*64 + nt*16 + l15;
      ctx[((long)(b*1024+q))*512 + cc] = (bf16)(cacc[nt][r] / lr[r]);
    }
}

// ---------------- gate1 tap-partial reduce + bias + relu ----------------
__global__ __launch_bounds__(256) void k_g1red(KParams p)
{
  long o = (long)blockIdx.x*256 + threadIdx.x;   // [b][m][n], 262144
  const float* part = (const float*)(p.ws+OFF_G1P);
  int m = (int)((o >> 10) & 31);
  float a = p.gb1[m];
  #pragma unroll
  for (int t=0;t<9;++t) a += part[(long)t*262144 + o];
  ((float*)(p.ws+OFF_Y1))[o] = fmaxf(a, 0.f);
}

// ---------------- gate2 + sigmoid + sum -> gsum[b][p] ----------------
__global__ __launch_bounds__(256)
void k_g2(KParams p, const float* gw2, const float* gb2)
{
  __shared__ float st[3*32*32];
  __shared__ float sg[2][32];
  int h = blockIdx.x, b = blockIdx.y;
  const float* y1 = (const float*)(p.ws+OFF_Y1) + (long)b*32768;
  int tid = threadIdx.x;
  for (int c = tid; c < 768; c += 256) {
    int e = c*4;
    int hr = e>>10, hid = (e>>5)&31, w = e&31;
    int hh = h + hr - 1;
    float4 v = {0,0,0,0};
    if ((unsigned)hh < 32u) v = *(const float4*)(y1 + hid*1024 + hh*32 + w);
    *(float4*)&st[e] = v;
  }
  __syncthreads();
  if (tid < 64) {
    int gg = tid>>5, w = tid&31;
    float acc = gb2[gg];
    for (int hid=0; hid<32; ++hid) {
      #pragma unroll
      for (int u=0;u<3;++u) {
        #pragma unroll
        for (int v=0;v<3;++v) {
          int ww = w + v - 1;
          if ((unsigned)ww < 32u)
            acc += st[(u*32+hid)*32 + ww] * gw2[((gg*32+hid)*3+u)*3+v];
        }
      }
    }
    sg[gg][w] = 1.f/(1.f+__expf(-acc));
  }
  __syncthreads();
  if (tid < 32) ((float*)(p.ws+OFF_GSUM))[b*1024 + h*32 + tid] = sg[0][tid]+sg[1][tid];
}

// ---------------- dynamic 5x5 depthwise conv + gated fuse -> fused2[b][p][c] ----------------
__global__ __launch_bounds__(512)
void k_dyn(KParams p)
{
  __shared__ float ffs[16*1024];
  int ct = blockIdx.x;            // 0..31
  int b  = blockIdx.y;            // 0..7
  int c0 = ct*16;
  int t = threadIdx.x;            // 512
  const bf16* ffg = (const bf16*)(p.ws+OFF_FF) + ((long)(b*512 + c0))*1024;
  #pragma unroll
  for (int k2 = 0; k2 < 4; ++k2) {
    int chunk = t + 512*k2;
    int c = chunk >> 7, j = chunk & 127;
    bf16x8 v = *(const bf16x8*)(ffg + (long)c*1024 + j*8);
    float* d = ffs + c*1024 + j*8;
    #pragma unroll
    for (int e=0;e<8;++e) d[e] = (float)v[e];
  }
  const float* kwp = (const float*)(p.ws+OFF_KW) + b*32;
  float kk[25];
  #pragma unroll
  for (int j=0;j<25;++j) kk[j] = kwp[j];
  __syncthreads();
  int w = t & 31;
  int h0 = t >> 5;                // 0..15
  #pragma unroll
  for (int pass=0; pass<2; ++pass) {
    int h = h0 + pass*16;
    int pos = h*32 + w;
    float gsw = ((const float*)(p.ws+OFF_GSUM))[b*1024 + pos];
    const float* vip = p.vi + ((long)(b*512 + c0))*1024 + pos;
    const float* irp = p.ir + ((long)(b*512 + c0))*1024 + pos;
    bf16 outv[16];
    #pragma unroll
    for (int c=0;c<16;++c) {
      float dyn = 0.f;
      #pragma unroll
      for (int u=0;u<5;++u) {
        int hh = h+u-2;
        bool okh = (unsigned)hh < 32u;
        #pragma unroll
        for (int v=0;v<5;++v) {
          int ww = w+v-2;
          bool ok = okh && ((unsigned)ww < 32u);
          float fv = ffs[c*1024 + (hh&31)*32 + (ww&31)];
          dyn += (ok ? fv : 0.f) * kk[u*5+v];
        }
      }
      float val = gsw*dyn + vip[(long)c*1024] + irp[(long)c*1024];
      outv[c] = (bf16)val;
    }
    bf16* f2 = (bf16*)(p.ws+OFF_F2) + ((long)(b*1024 + pos))*512 + c0;
    *(bf16x8*)f2       = *(bf16x8*)&outv[0];
    *((bf16x8*)f2 + 1) = *(bf16x8*)&outv[8];
  }
}

extern "C" void kernel_launch(void* const* d_in, const int* in_sizes, int n_in,
                              void* d_out, int out_size, void* d_ws, size_t ws_size,
                              hipStream_t stream)
{
  char* ws = (char*)d_ws;
  KParams p;
  p.vi = (const float*)d_in[0];  p.ir = (const float*)d_in[1];
  p.bq = (const float*)d_in[7];  p.bk = (const float*)d_in[9];
  p.bv = (const float*)d_in[11]; p.bo = (const float*)d_in[13];
  p.gb1 = (const float*)d_in[15];
  p.ws = ws; p.out = (float*)d_out;

  k_wprep<<<14467,256,0,stream>>>((const float*)d_in[6],(const float*)d_in[8],(const float*)d_in[10],(const float*)d_in[12],
      (const float*)d_in[18],(const float*)d_in[14],(const float*)d_in[19],(const float*)d_in[20],(const float*)d_in[21],
      (const float*)d_in[22],(const float*)d_in[23],
      (bf16*)(ws+OFF_WBF),(bf16*)(ws+OFF_ENHW),(bf16*)(ws+OFF_GW1R),(float*)(ws+OFF_CHS),(float*)(ws+OFF_ZP));
  k_cat<<<dim3(8,32,8),256,0,stream>>>(p.vi, p.ir, (bf16*)(ws+OFF_CATSEQ));
  k_pool<<<4096,256,0,stream>>>(p.vi,p.ir,(float*)(ws+OFF_POOL));
  k_mlp1<<<64,256,0,stream>>>((const float*)(ws+OFF_POOL),(const float*)d_in[2],(const float*)d_in[3],(float*)(ws+OFF_HID));
  k_mlp2<<<8,256,0,stream>>>((const float*)(ws+OFF_HID),(const float*)d_in[4],(const float*)d_in[5],(float*)(ws+OFF_KW));
  k_gemm<0,128,128,2,16><<<dim3(8,4,24),256,0,stream>>>(p);
  k_attn<<<dim3(16,8,8),256,0,stream>>>(p);
  k_gemm<1,64,128,2,16><<<dim3(8,8,8),256,0,stream>>>(p);
  k_gemm<3,32,256,1,32><<<dim3(4,1,72),256,0,stream>>>(p);
  k_g1red<<<1024,256,0,stream>>>(p);
  k_g2<<<dim3(32,8),256,0,stream>>>(p,(const float*)d_in[16],(const float*)d_in[17]);
  k_dyn<<<dim3(32,8),512,0,stream>>>(p);
  k_gemm<2,128,128,2,72><<<dim3(8,4,16),256,0,stream>>>(p);
  k_enhred<<<4096,256,0,stream>>>(p);
}

// Round 4
// 369.071 us; speedup vs baseline: 2.0734x; 1.0392x over previous
//
#include <hip/hip_runtime.h>
#include <math.h>

typedef __bf16 bf16;
typedef __attribute__((ext_vector_type(8))) __bf16 bf16x8;
typedef __attribute__((ext_vector_type(4))) float f32x4;

// ---------------- workspace layout (bytes) ----------------
constexpr size_t OFF_CATSEQ = 0;          // 16777216  [b][p][c(0:512 vi,512:1024 ir)] bf16
constexpr size_t OFF_WBF    = 16777216;   // 2097152   Wq,Wk,Wv,Wo bf16 [co][c]
constexpr size_t OFF_ENHW   = 18874368;   // 4718592   enh_w repacked [t][co][ci] bf16
constexpr size_t OFF_GW1R   = 23592960;   // 589824    gate_w1 repacked [t][hid][ci] bf16
constexpr size_t OFF_CHS    = 24182784;   // 4096      bn scale[512], shift[512]
constexpr size_t OFF_ZP     = 24186880;   // 256       zero page
constexpr size_t OFF_POOL   = 24187136;   // 16384
constexpr size_t OFF_HID    = 24203520;   // 65536
constexpr size_t OFF_KW     = 24269056;   // 1024
constexpr size_t OFF_Q      = 24270080;   // 8388608  [b][h][p][d] bf16 (x0.125); reused as enh partial kg=0 (f32)
constexpr size_t OFF_K      = 32658688;   // 8388608  [b][h][p][d] bf16
constexpr size_t OFF_VT     = 41047296;   // 8388608  [b][h][d][p] bf16; reused as enh partial kg=1
constexpr size_t OFF_CTX    = 49435904;   // 8388608  [b][p][c] bf16
constexpr size_t OFF_FF     = 57824512;   // 8388608  fused_feat [b][c][p] bf16
constexpr size_t OFF_G1P    = 66213120;   // 9437184  gate1 partials [t][b][32][1024] f32
constexpr size_t OFF_Y1     = 75650304;   // 1048576  y1 [b][32][1024] f32
constexpr size_t OFF_GSUM   = 76698880;   // 32768    [b][p] f32
constexpr size_t OFF_F2     = 76731648;   // 8388608  fused2 [b][p][c] bf16
// total 85120256 bytes

struct KParams {
  const float *vi, *ir, *bq, *bk, *bv, *bo, *gb1;
  char* ws;
  float* out;
};

__device__ __forceinline__ void gload16(const void* g, void* l) {
  __builtin_amdgcn_global_load_lds(
      (const __attribute__((address_space(1))) unsigned int*)g,
      (__attribute__((address_space(3))) unsigned int*)l, 16, 0, 0);
}

// ---------------- weight prep ----------------
__global__ void k_wprep(const float* Wq, const float* Wk, const float* Wv, const float* Wo,
                        const float* enh_w, const float* gw1,
                        const float* enh_b, const float* gamma, const float* beta,
                        const float* mean, const float* var,
                        bf16* wbf, bf16* enhw, bf16* gw1r, float* chs, float* zp)
{
  long i = (long)blockIdx.x*256 + threadIdx.x;
  if (i < 1048576) {
    int which = (int)(i >> 18); long r = i & 262143;
    const float* s = which==0?Wq: which==1?Wk: which==2?Wv:Wo;
    wbf[i] = (bf16)s[r];
  } else if (i < 1048576+2359296) {
    long j = i - 1048576; long t = j/262144; long r = j%262144;   // r = co*512+ci
    enhw[j] = (bf16)enh_w[r*9 + t];
  } else if (i < 1048576+2359296+294912) {
    long j = i - (1048576+2359296); long t = j/32768; long r = j%32768; // r = hid*1024+ci
    gw1r[j] = (bf16)gw1[r*9 + t];
  } else if (i < 1048576+2359296+294912+512) {
    int c = (int)(i - (1048576+2359296+294912));
    float sc = gamma[c]*rsqrtf(var[c]+1e-5f);
    chs[c] = sc; chs[512+c] = (enh_b[c]-mean[c])*sc + beta[c];
  } else if (i < 1048576+2359296+294912+512+64) {
    zp[i - (1048576+2359296+294912+512)] = 0.f;
  }
}

// ---------------- transpose-cast vi/ir -> catseq[b][p][1024] bf16 ----------------
__global__ __launch_bounds__(256) void k_cat(const float* vi, const float* ir, bf16* cat)
{
  __shared__ float ld[32][129];
  int pt = blockIdx.x, ct = blockIdx.y, b = blockIdx.z;
  const float* src = (ct < 16) ? vi : ir;
  int c0 = (ct & 15) * 32;
  int tid = threadIdx.x;
  int p0 = pt * 128;
  for (int it = 0; it < 4; ++it) {
    int row = it*8 + (tid>>5);
    int pc  = (tid & 31) * 4;
    float4 v = *(const float4*)(src + ((long)(b*512 + c0 + row))*1024 + p0 + pc);
    ld[row][pc+0]=v.x; ld[row][pc+1]=v.y; ld[row][pc+2]=v.z; ld[row][pc+3]=v.w;
  }
  __syncthreads();
  int p = tid >> 1, half = tid & 1;
  bf16x8 o0, o1;
  #pragma unroll
  for (int j = 0; j < 8; ++j) o0[j] = (bf16)ld[half*16 + j][p];
  #pragma unroll
  for (int j = 0; j < 8; ++j) o1[j] = (bf16)ld[half*16 + 8 + j][p];
  long ccol = (ct<16 ? 0 : 512) + c0 + half*16;
  bf16* dst = cat + ((long)(b*1024 + p0 + p))*1024 + ccol;
  *(bf16x8*)dst       = o0;
  *((bf16x8*)dst + 1) = o1;
}

// ---------------- pooled[b][c] ----------------
__global__ __launch_bounds__(256) void k_pool(const float* vi, const float* ir, float* pooled)
{
  int bc = blockIdx.x;
  int tid = threadIdx.x;
  float4 a = ((const float4*)(vi + (long)bc*1024))[tid];
  float4 c = ((const float4*)(ir + (long)bc*1024))[tid];
  float s = a.x+a.y+a.z+a.w + c.x+c.y+c.z+c.w;
  #pragma unroll
  for (int off=32; off; off>>=1) s += __shfl_down(s, off);
  __shared__ float wsum[4];
  if ((tid&63)==0) wsum[tid>>6] = s;
  __syncthreads();
  if (tid==0) pooled[bc] = (wsum[0]+wsum[1]+wsum[2]+wsum[3]) * (1.f/1024.f);
}

// ---------------- mlp1 ----------------
__global__ __launch_bounds__(256) void k_mlp1(const float* pooled, const float* w1, const float* b1, float* hid)
{
  __shared__ float pl[512];
  int blk = blockIdx.x; int b = blk >> 3, ch = blk & 7;
  int tid = threadIdx.x;
  ((float2*)pl)[tid] = ((const float2*)(pooled + b*512))[tid];
  __syncthreads();
  int i = ch*256 + tid;
  const float* wr = w1 + (long)i*512;
  float acc = b1[i];
  #pragma unroll 8
  for (int c = 0; c < 512; ++c) acc += pl[c]*wr[c];
  hid[b*2048 + i] = fmaxf(acc, 0.f);
}

// ---------------- mlp2 + softmax -> kw[b][25] ----------------
__global__ __launch_bounds__(256) void k_mlp2(const float* hid, const float* w2, const float* b2, float* kw)
{
  __shared__ float hd[2048];
  __shared__ float lg[32];
  int b = blockIdx.x, tid = threadIdx.x, lane = tid&63, wave = tid>>6;
  ((float2*)hd)[tid]     = ((const float2*)(hid + b*2048))[tid];
  ((float2*)hd)[tid+256] = ((const float2*)(hid + b*2048))[tid+256];
  __syncthreads();
  for (int j = wave; j < 25; j += 4) {
    const float* wr = w2 + (long)j*2048;
    float acc = 0;
    for (int i = lane; i < 2048; i += 64) acc += hd[i]*wr[i];
    #pragma unroll
    for (int off=32; off; off>>=1) acc += __shfl_down(acc, off);
    if (lane==0) lg[j] = acc + b2[j];
  }
  __syncthreads();
  if (tid==0) {
    float mx = lg[0];
    for (int j=1;j<25;++j) mx = fmaxf(mx, lg[j]);
    float s = 0.f; float e[25];
    for (int j=0;j<25;++j){ e[j]=__expf(lg[j]-mx); s+=e[j]; }
    float inv = 1.f/s;
    for (int j=0;j<25;++j) kw[b*32+j] = e[j]*inv;
  }
}

// ---------------- generic TN bf16 MFMA GEMM (2-phase prefetch, XCD-chunked decode) ----------------
// OP 0: QKV   flat 768:  b=wg&7, which=wg>>8,        xy=(wg>>3)&31
// OP 1: Wo    flat 512:  b=wg&7, xy=wg>>3 (0..63)
// OP 2: enh   flat 512:  b=wg&7, kg=(wg>>3)>>5, xy=(wg>>3)&31
// OP 3: gate1 flat 288:  b=wg&7, tap=(wg>>3)>>2, x=(wg>>3)&3
template<int OP, int BM, int BN, int WAVES_M, int KSTEPS>
__global__ __launch_bounds__(256)
void k_gemm(KParams p)
{
  constexpr int WAVES_N = 4/WAVES_M;
  constexpr int MT = BM/(WAVES_M*16);
  constexpr int NT = BN/(WAVES_N*16);
  __shared__ bf16 As[2][BM*32];
  __shared__ bf16 Bs[2][BN*32];
  const int tid = threadIdx.x, lane = tid&63, wave = tid>>6;
  const int g = lane>>4, l15 = lane&15;
  const int wm = wave % WAVES_M, wn = wave / WAVES_M;

  int b, which = 0, tap = 0, kg = 0, m0, n0;
  const bf16 *Aptr, *Bptr;
  long ldb, lda;
  const int wg = blockIdx.x;
  if constexpr (OP==0) {
    b = wg&7; which = wg>>8;
    int xy = (wg>>3)&31;
    m0 = (xy>>3)*BM; n0 = (xy&7)*BN;
    Aptr = (const bf16*)(p.ws+OFF_WBF) + (long)which*262144;
    Bptr = (const bf16*)(p.ws+OFF_CATSEQ) + (long)b*1048576 + (which?512:0);
    ldb = 1024; lda = 512;
  } else if constexpr (OP==1) {
    b = wg&7;
    int xy = wg>>3;
    m0 = (xy>>3)*BM; n0 = (xy&7)*BN;
    Aptr = (const bf16*)(p.ws+OFF_WBF) + 3L*262144;
    Bptr = (const bf16*)(p.ws+OFF_CTX) + (long)b*524288;
    ldb = 512; lda = 512;
  } else if constexpr (OP==2) {
    b = wg&7;
    int loc = wg>>3;
    kg = loc>>5;
    int xy = loc&31;
    m0 = (xy>>3)*BM; n0 = (xy&7)*BN;
    Aptr = (const bf16*)(p.ws+OFF_ENHW);
    Bptr = (const bf16*)(p.ws+OFF_F2) + (long)b*524288;
    ldb = 512; lda = 512;
  } else {
    b = wg&7;
    int loc = wg>>3;
    tap = loc>>2;
    m0 = 0; n0 = (loc&3)*BN;
    Aptr = (const bf16*)(p.ws+OFF_GW1R) + (long)tap*32768;
    Bptr = (const bf16*)(p.ws+OFF_CATSEQ) + (long)b*1048576;
    ldb = 1024; lda = 1024;
  }
  const bf16* zp = (const bf16*)(p.ws+OFF_ZP);

  auto STAGE = [&](int buf, int ks) {
    int t, kc;
    if constexpr (OP==2) { int gks = kg*72 + ks; t = gks>>4; kc = gks&15; }
    else if constexpr (OP==3) { t = tap; kc = ks; }
    else { t = 0; kc = ks; }
    for (int c = tid; c < BM*4; c += 256) {
      int row = c>>2, slot = c&3;
      int ss = slot ^ ((row>>1)&3);
      const bf16* src;
      if constexpr (OP==2) src = Aptr + (long)t*262144 + (long)(m0+row)*lda + kc*32 + ss*8;
      else                 src = Aptr + (long)(m0+row)*lda + kc*32 + ss*8;
      gload16(src, As[buf] + (long)(c-lane)*8);
    }
    for (int c = tid; c < BN*4; c += 256) {
      int row = c>>2, slot = c&3;
      int ss = slot ^ ((row>>1)&3);
      const bf16* src;
      if constexpr (OP==2 || OP==3) {
        int pp = n0 + row;
        int hh = (pp>>5) + t/3 - 1, ww = (pp&31) + t%3 - 1;
        bool valid = ((unsigned)hh < 32u) && ((unsigned)ww < 32u);
        src = valid ? (Bptr + (long)(hh*32+ww)*ldb + kc*32 + ss*8) : zp;
      } else {
        src = Bptr + (long)(n0+row)*ldb + kc*32 + ss*8;
      }
      gload16(src, Bs[buf] + (long)(c-lane)*8);
    }
  };

  f32x4 acc[MT][NT] = {};

  STAGE(0, 0);
  __syncthreads();
  int cur = 0;
  #pragma unroll 2
  for (int ks = 0; ks < KSTEPS; ++ks) {
    if (ks+1 < KSTEPS) STAGE(cur^1, ks+1);
    bf16x8 af[MT], bq_[NT];
    #pragma unroll
    for (int mt=0; mt<MT; ++mt) {
      int row = wm*MT*16 + mt*16 + l15;
      af[mt] = *(const bf16x8*)&As[cur][row*32 + 8*(g ^ ((row>>1)&3))];
    }
    #pragma unroll
    for (int nt=0; nt<NT; ++nt) {
      int row = wn*NT*16 + nt*16 + l15;
      bq_[nt] = *(const bf16x8*)&Bs[cur][row*32 + 8*(g ^ ((row>>1)&3))];
    }
    __builtin_amdgcn_s_setprio(1);
    #pragma unroll
    for (int mt=0; mt<MT; ++mt)
      #pragma unroll
      for (int nt=0; nt<NT; ++nt)
        acc[mt][nt] = __builtin_amdgcn_mfma_f32_16x16x32_bf16(af[mt], bq_[nt], acc[mt][nt], 0,0,0);
    __builtin_amdgcn_s_setprio(0);
    __syncthreads();
    cur ^= 1;
  }

  #pragma unroll
  for (int mt=0; mt<MT; ++mt) {
    #pragma unroll
    for (int nt=0; nt<NT; ++nt) {
      #pragma unroll
      for (int reg=0; reg<4; ++reg) {
        int m = m0 + wm*MT*16 + mt*16 + 4*g + reg;
        int n = n0 + wn*NT*16 + nt*16 + l15;
        float v = acc[mt][nt][reg];
        if constexpr (OP==0) {
          const float* bias = which==0?p.bq: which==1?p.bk:p.bv;
          v += bias[m];
          if (which==0) v *= 0.125f;
          int h = m>>6, d = m&63;
          if (which==2) ((bf16*)(p.ws+OFF_VT))[((long)(b*8+h)*64 + d)*1024 + n] = (bf16)v;
          else {
            bf16* dst = (bf16*)(p.ws + (which==0?OFF_Q:OFF_K));
            dst[((long)(b*8+h)*1024 + n)*64 + d] = (bf16)v;
          }
        } else if constexpr (OP==1) {
          v += p.bo[m];
          ((bf16*)(p.ws+OFF_FF))[((long)(b*512+m))*1024 + n] = (bf16)v;
        } else if constexpr (OP==2) {
          float* part = (float*)(p.ws+OFF_Q) + (long)kg*4194304;
          part[((long)b*512+m)*1024 + n] = v;
        } else {
          ((float*)(p.ws+OFF_G1P))[((long)((tap*8+b)*32+m))*1024 + n] = v;
        }
      }
    }
  }
}

// ---------------- enh split-K reduce + BN + SiLU -> out ----------------
__global__ __launch_bounds__(256) void k_enhred(KParams p)
{
  long e = ((long)blockIdx.x*256 + threadIdx.x)*4;
  const float* part = (const float*)(p.ws+OFF_Q);
  float4 a = *(const float4*)(part + e);
  float4 c = *(const float4*)(part + 4194304 + e);
  int m = (int)((e>>10)&511);
  const float* chs = (const float*)(p.ws+OFF_CHS);
  float sc = chs[m], sh = chs[512+m];
  float4 o;
  float y0 = (a.x+c.x)*sc+sh, y1 = (a.y+c.y)*sc+sh, y2 = (a.z+c.z)*sc+sh, y3 = (a.w+c.w)*sc+sh;
  o.x = y0/(1.f+__expf(-y0)); o.y = y1/(1.f+__expf(-y1));
  o.z = y2/(1.f+__expf(-y2)); o.w = y3/(1.f+__expf(-y3));
  *(float4*)(p.out + e) = o;
}

// ---------------- flash attention (KVBLK=64, dbuf prefetch, defer-max, XCD-chunked) ----------------
__global__ __launch_bounds__(256)
void k_attn(KParams p)
{
  const bf16* Q = (const bf16*)(p.ws+OFF_Q);
  const bf16* K = (const bf16*)(p.ws+OFF_K);
  const bf16* V = (const bf16*)(p.ws+OFF_VT);
  bf16* ctx = (bf16*)(p.ws+OFF_CTX);
  // XCD-chunked: all 16 qt blocks of a (b,h) land on one XCD
  int wg = blockIdx.x;
  int bh = (wg&7)*8 + (wg>>7);
  int qt = (wg>>3)&15;
  int b = bh>>3, h = bh&7;
  int tid = threadIdx.x, lane = tid&63, wave = tid>>6, g = lane>>4, l15 = lane&15;
  __shared__ bf16 Ks[2][64*64];
  __shared__ bf16 Vs[2][64*64];
  __shared__ bf16 Ps[4][16*64];
  const bf16* Qw = Q + ((long)bh*1024 + qt*64 + wave*16)*64;
  bf16x8 qf[2];
  qf[0] = *(const bf16x8*)(Qw + l15*64 + g*8);
  qf[1] = *(const bf16x8*)(Qw + l15*64 + 32 + g*8);
  const bf16* Kb = K + (long)bh*65536;
  const bf16* Vb = V + (long)bh*65536;
  float mr[4] = {-1e30f,-1e30f,-1e30f,-1e30f};
  float lr[4] = {0,0,0,0};
  f32x4 cacc[4] = {};

  auto STAGE = [&](int buf, int kv0) {
    #pragma unroll
    for (int c0 = 0; c0 < 512; c0 += 256) {
      int c = c0 + tid;
      int row = c>>3, slot = c&7, ss = slot ^ (row&7);
      gload16(Kb + (long)(kv0+row)*64 + ss*8, Ks[buf] + (long)(c-lane)*8);
    }
    #pragma unroll
    for (int c0 = 0; c0 < 512; c0 += 256) {
      int c = c0 + tid;
      int d = c>>3, slot = c&7, ss = slot ^ (d&7);
      gload16(Vb + (long)d*1024 + kv0 + ss*8, Vs[buf] + (long)(c-lane)*8);
    }
  };

  STAGE(0, 0);
  __syncthreads();
  int cur = 0;
  for (int step = 0; step < 16; ++step) {
    if (step < 15) STAGE(cur^1, (step+1)*64);
    // QK^T: s[sn][r] = score(q = 4g+r, kv = sn*16+l15)
    f32x4 s0 = {}, s1 = {}, s2 = {}, s3 = {};
    __builtin_amdgcn_s_setprio(1);
    {
      int r0 = l15, r1 = 16+l15, r2 = 32+l15, r3 = 48+l15;
      #pragma unroll
      for (int ks2=0; ks2<2; ++ks2) {
        bf16x8 kf0 = *(const bf16x8*)&Ks[cur][r0*64 + 8*((4*ks2+g)^(r0&7))];
        bf16x8 kf1 = *(const bf16x8*)&Ks[cur][r1*64 + 8*((4*ks2+g)^(r1&7))];
        bf16x8 kf2 = *(const bf16x8*)&Ks[cur][r2*64 + 8*((4*ks2+g)^(r2&7))];
        bf16x8 kf3 = *(const bf16x8*)&Ks[cur][r3*64 + 8*((4*ks2+g)^(r3&7))];
        s0 = __builtin_amdgcn_mfma_f32_16x16x32_bf16(qf[ks2], kf0, s0, 0,0,0);
        s1 = __builtin_amdgcn_mfma_f32_16x16x32_bf16(qf[ks2], kf1, s1, 0,0,0);
        s2 = __builtin_amdgcn_mfma_f32_16x16x32_bf16(qf[ks2], kf2, s2, 0,0,0);
        s3 = __builtin_amdgcn_mfma_f32_16x16x32_bf16(qf[ks2], kf3, s3, 0,0,0);
      }
    }
    __builtin_amdgcn_s_setprio(0);
    // online softmax with deferred rescale
    float pmax[4];
    #pragma unroll
    for (int r=0;r<4;++r) {
      float x = fmaxf(fmaxf(s0[r],s1[r]), fmaxf(s2[r],s3[r]));
      x = fmaxf(x, __shfl_xor(x, 1));
      x = fmaxf(x, __shfl_xor(x, 2));
      x = fmaxf(x, __shfl_xor(x, 4));
      x = fmaxf(x, __shfl_xor(x, 8));
      pmax[r] = x;
    }
    bool need = (pmax[0] > mr[0]+8.f) | (pmax[1] > mr[1]+8.f) |
                (pmax[2] > mr[2]+8.f) | (pmax[3] > mr[3]+8.f);
    if (__any(need)) {
      #pragma unroll
      for (int r=0;r<4;++r) {
        float mn = fmaxf(mr[r], pmax[r]);
        float al = __expf(mr[r]-mn);
        mr[r] = mn; lr[r] *= al;
        cacc[0][r]*=al; cacc[1][r]*=al; cacc[2][r]*=al; cacc[3][r]*=al;
      }
    }
    bf16* Pw = Ps[wave];
    #pragma unroll
    for (int r=0;r<4;++r) {
      float p0 = __expf(s0[r]-mr[r]);
      float p1 = __expf(s1[r]-mr[r]);
      float p2 = __expf(s2[r]-mr[r]);
      float p3 = __expf(s3[r]-mr[r]);
      int q = 4*g + r;
      int xr = 8*(q&7);
      Pw[q*64 + ((     l15) ^ xr)] = (bf16)p0;
      Pw[q*64 + ((16 + l15) ^ xr)] = (bf16)p1;
      Pw[q*64 + ((32 + l15) ^ xr)] = (bf16)p2;
      Pw[q*64 + ((48 + l15) ^ xr)] = (bf16)p3;
      float sum = (p0+p1)+(p2+p3);
      sum += __shfl_xor(sum, 1);
      sum += __shfl_xor(sum, 2);
      sum += __shfl_xor(sum, 4);
      sum += __shfl_xor(sum, 8);
      lr[r] += sum;
    }
    // PV
    bf16x8 pa0 = *(const bf16x8*)&Pw[l15*64 + 8*((  g)^(l15&7))];
    bf16x8 pa1 = *(const bf16x8*)&Pw[l15*64 + 8*((4+g)^(l15&7))];
    __builtin_amdgcn_s_setprio(1);
    #pragma unroll
    for (int nt=0;nt<4;++nt) {
      int d = nt*16 + l15;
      bf16x8 vf0 = *(const bf16x8*)&Vs[cur][d*64 + 8*((  g)^(d&7))];
      bf16x8 vf1 = *(const bf16x8*)&Vs[cur][d*64 + 8*((4+g)^(d&7))];
      cacc[nt] = __builtin_amdgcn_mfma_f32_16x16x32_bf16(pa0, vf0, cacc[nt], 0,0,0);
      cacc[nt] = __builtin_amdgcn_mfma_f32_16x16x32_bf16(pa1, vf1, cacc[nt], 0,0,0);
    }
    __builtin_amdgcn_s_setprio(0);
    __syncthreads();
    cur ^= 1;
  }
  #pragma unroll
  for (int nt=0;nt<4;++nt) {
    #pragma unroll
    for (int r=0;r<4;++r) {
      int q = qt*64 + wave*16 + 4*g + r;
      int cc = h*64 + nt*16 + l15;
      ctx[((long)(b*1024+q))*512 + cc] = (bf16)(cacc[nt][r] / lr[r]);
    }
  }
}

// ---------------- gate1 tap-partial reduce + bias + relu ----------------
__global__ __launch_bounds__(256) void k_g1red(KParams p)
{
  long o = (long)blockIdx.x*256 + threadIdx.x;   // [b][m][n], 262144
  const float* part = (const float*)(p.ws+OFF_G1P);
  int m = (int)((o >> 10) & 31);
  float a = p.gb1[m];
  #pragma unroll
  for (int t=0;t<9;++t) a += part[(long)t*262144 + o];
  ((float*)(p.ws+OFF_Y1))[o] = fmaxf(a, 0.f);
}

// ---------------- gate2 + sigmoid + sum -> gsum[b][p] ----------------
__global__ __launch_bounds__(256)
void k_g2(KParams p, const float* gw2, const float* gb2)
{
  __shared__ float st[3*32*32];
  __shared__ float sg[2][32];
  int h = blockIdx.x, b = blockIdx.y;
  const float* y1 = (const float*)(p.ws+OFF_Y1) + (long)b*32768;
  int tid = threadIdx.x;
  for (int c = tid; c < 768; c += 256) {
    int e = c*4;
    int hr = e>>10, hid = (e>>5)&31, w = e&31;
    int hh = h + hr - 1;
    float4 v = {0,0,0,0};
    if ((unsigned)hh < 32u) v = *(const float4*)(y1 + hid*1024 + hh*32 + w);
    *(float4*)&st[e] = v;
  }
  __syncthreads();
  if (tid < 64) {
    int gg = tid>>5, w = tid&31;
    float acc = gb2[gg];
    for (int hid=0; hid<32; ++hid) {
      #pragma unroll
      for (int u=0;u<3;++u) {
        #pragma unroll
        for (int v=0;v<3;++v) {
          int ww = w + v - 1;
          if ((unsigned)ww < 32u)
            acc += st[(u*32+hid)*32 + ww] * gw2[((gg*32+hid)*3+u)*3+v];
        }
      }
    }
    sg[gg][w] = 1.f/(1.f+__expf(-acc));
  }
  __syncthreads();
  if (tid < 32) ((float*)(p.ws+OFF_GSUM))[b*1024 + h*32 + tid] = sg[0][tid]+sg[1][tid];
}

// ---------------- dynamic 5x5 depthwise conv + gated fuse -> fused2[b][p][c] ----------------
__global__ __launch_bounds__(512)
void k_dyn(KParams p)
{
  __shared__ float ffs[16*1024];
  int ct = blockIdx.x;            // 0..31
  int b  = blockIdx.y;            // 0..7
  int c0 = ct*16;
  int t = threadIdx.x;            // 512
  const bf16* ffg = (const bf16*)(p.ws+OFF_FF) + ((long)(b*512 + c0))*1024;
  #pragma unroll
  for (int k2 = 0; k2 < 4; ++k2) {
    int chunk = t + 512*k2;
    int c = chunk >> 7, j = chunk & 127;
    bf16x8 v = *(const bf16x8*)(ffg + (long)c*1024 + j*8);
    float* d = ffs + c*1024 + j*8;
    #pragma unroll
    for (int e=0;e<8;++e) d[e] = (float)v[e];
  }
  const float* kwp = (const float*)(p.ws+OFF_KW) + b*32;
  float kk[25];
  #pragma unroll
  for (int j=0;j<25;++j) kk[j] = kwp[j];
  __syncthreads();
  int w = t & 31;
  int h0 = t >> 5;                // 0..15
  #pragma unroll
  for (int pass=0; pass<2; ++pass) {
    int h = h0 + pass*16;
    int pos = h*32 + w;
    float gsw = ((const float*)(p.ws+OFF_GSUM))[b*1024 + pos];
    const float* vip = p.vi + ((long)(b*512 + c0))*1024 + pos;
    const float* irp = p.ir + ((long)(b*512 + c0))*1024 + pos;
    bf16 outv[16];
    #pragma unroll
    for (int c=0;c<16;++c) {
      float dyn = 0.f;
      #pragma unroll
      for (int u=0;u<5;++u) {
        int hh = h+u-2;
        bool okh = (unsigned)hh < 32u;
        #pragma unroll
        for (int v=0;v<5;++v) {
          int ww = w+v-2;
          bool ok = okh && ((unsigned)ww < 32u);
          float fv = ffs[c*1024 + (hh&31)*32 + (ww&31)];
          dyn += (ok ? fv : 0.f) * kk[u*5+v];
        }
      }
      float val = gsw*dyn + vip[(long)c*1024] + irp[(long)c*1024];
      outv[c] = (bf16)val;
    }
    bf16* f2 = (bf16*)(p.ws+OFF_F2) + ((long)(b*1024 + pos))*512 + c0;
    *(bf16x8*)f2       = *(bf16x8*)&outv[0];
    *((bf16x8*)f2 + 1) = *(bf16x8*)&outv[8];
  }
}

extern "C" void kernel_launch(void* const* d_in, const int* in_sizes, int n_in,
                              void* d_out, int out_size, void* d_ws, size_t ws_size,
                              hipStream_t stream)
{
  char* ws = (char*)d_ws;
  KParams p;
  p.vi = (const float*)d_in[0];  p.ir = (const float*)d_in[1];
  p.bq = (const float*)d_in[7];  p.bk = (const float*)d_in[9];
  p.bv = (const float*)d_in[11]; p.bo = (const float*)d_in[13];
  p.gb1 = (const float*)d_in[15];
  p.ws = ws; p.out = (float*)d_out;

  k_wprep<<<14467,256,0,stream>>>((const float*)d_in[6],(const float*)d_in[8],(const float*)d_in[10],(const float*)d_in[12],
      (const float*)d_in[18],(const float*)d_in[14],(const float*)d_in[19],(const float*)d_in[20],(const float*)d_in[21],
      (const float*)d_in[22],(const float*)d_in[23],
      (bf16*)(ws+OFF_WBF),(bf16*)(ws+OFF_ENHW),(bf16*)(ws+OFF_GW1R),(float*)(ws+OFF_CHS),(float*)(ws+OFF_ZP));
  k_cat<<<dim3(8,32,8),256,0,stream>>>(p.vi, p.ir, (bf16*)(ws+OFF_CATSEQ));
  k_pool<<<4096,256,0,stream>>>(p.vi,p.ir,(float*)(ws+OFF_POOL));
  k_mlp1<<<64,256,0,stream>>>((const float*)(ws+OFF_POOL),(const float*)d_in[2],(const float*)d_in[3],(float*)(ws+OFF_HID));
  k_mlp2<<<8,256,0,stream>>>((const float*)(ws+OFF_HID),(const float*)d_in[4],(const float*)d_in[5],(float*)(ws+OFF_KW));
  k_gemm<0,128,128,2,16><<<768,256,0,stream>>>(p);
  k_attn<<<1024,256,0,stream>>>(p);
  k_gemm<1,64,128,2,16><<<512,256,0,stream>>>(p);
  k_gemm<3,32,256,1,32><<<288,256,0,stream>>>(p);
  k_g1red<<<1024,256,0,stream>>>(p);
  k_g2<<<dim3(32,8),256,0,stream>>>(p,(const float*)d_in[16],(const float*)d_in[17]);
  k_dyn<<<dim3(32,8),512,0,stream>>>(p);
  k_gemm<2,128,128,2,72><<<512,256,0,stream>>>(p);
  k_enhred<<<4096,256,0,stream>>>(p);
}

// Round 5
// 295.718 us; speedup vs baseline: 2.5877x; 1.2481x over previous
//
#include <hip/hip_runtime.h>
#include <math.h>

typedef __bf16 bf16;
typedef __attribute__((ext_vector_type(8))) __bf16 bf16x8;
typedef __attribute__((ext_vector_type(4))) float f32x4;

// ---------------- workspace layout (bytes) ----------------
constexpr size_t OFF_CATSEQ = 0;          // 16777216  [b][p][c(0:512 vi,512:1024 ir)] bf16
constexpr size_t OFF_WBF    = 16777216;   // 2097152   Wq,Wk,Wv,Wo bf16 [co][c]
constexpr size_t OFF_ENHW   = 18874368;   // 4718592   enh_w repacked [t][co][ci] bf16
constexpr size_t OFF_GW1R   = 23592960;   // 589824    gate_w1 repacked [t][hid][ci] bf16
constexpr size_t OFF_CHS    = 24182784;   // 4096      bn scale[512], shift[512]
constexpr size_t OFF_ZP     = 24186880;   // 256       zero page
constexpr size_t OFF_POOL   = 24187136;   // 16384
constexpr size_t OFF_HID    = 24203520;   // 65536
constexpr size_t OFF_KW     = 24269056;   // 1024
constexpr size_t OFF_Q      = 24270080;   // 8388608  [b][h][p][d] bf16 (x0.125); reused as enh partial kg=0 (f32)
constexpr size_t OFF_K      = 32658688;   // 8388608  [b][h][p][d] bf16
constexpr size_t OFF_VT     = 41047296;   // 8388608  [b][h][d][p] bf16; reused as enh partial kg=1
constexpr size_t OFF_CTX    = 49435904;   // 8388608  [b][p][c] bf16
constexpr size_t OFF_FF     = 57824512;   // 8388608  fused_feat [b][c][p] bf16
constexpr size_t OFF_G1P    = 66213120;   // 9437184  gate1 partials [t][b][32][1024] f32 (early: mlp2 logits scratch)
constexpr size_t OFF_Y1     = 75650304;   // 1048576  y1 [b][32][1024] f32
constexpr size_t OFF_GSUM   = 76698880;   // 32768    [b][p] f32
constexpr size_t OFF_F2     = 76731648;   // 8388608  fused2 [b][p][c] bf16
// total 85120256 bytes

struct KParams {
  const float *vi, *ir, *bq, *bk, *bv, *bo, *gb1;
  char* ws;
  float* out;
};

__device__ __forceinline__ void gload16(const void* g, void* l) {
  __builtin_amdgcn_global_load_lds(
      (const __attribute__((address_space(1))) unsigned int*)g,
      (__attribute__((address_space(3))) unsigned int*)l, 16, 0, 0);
}

// ---------------- weight prep ----------------
__global__ void k_wprep(const float* Wq, const float* Wk, const float* Wv, const float* Wo,
                        const float* enh_w, const float* gw1,
                        const float* enh_b, const float* gamma, const float* beta,
                        const float* mean, const float* var,
                        bf16* wbf, bf16* enhw, bf16* gw1r, float* chs, float* zp)
{
  long i = (long)blockIdx.x*256 + threadIdx.x;
  if (i < 1048576) {
    int which = (int)(i >> 18); long r = i & 262143;
    const float* s = which==0?Wq: which==1?Wk: which==2?Wv:Wo;
    wbf[i] = (bf16)s[r];
  } else if (i < 1048576+2359296) {
    long j = i - 1048576; long t = j/262144; long r = j%262144;   // r = co*512+ci
    enhw[j] = (bf16)enh_w[r*9 + t];
  } else if (i < 1048576+2359296+294912) {
    long j = i - (1048576+2359296); long t = j/32768; long r = j%32768; // r = hid*1024+ci
    gw1r[j] = (bf16)gw1[r*9 + t];
  } else if (i < 1048576+2359296+294912+512) {
    int c = (int)(i - (1048576+2359296+294912));
    float sc = gamma[c]*rsqrtf(var[c]+1e-5f);
    chs[c] = sc; chs[512+c] = (enh_b[c]-mean[c])*sc + beta[c];
  } else if (i < 1048576+2359296+294912+512+64) {
    zp[i - (1048576+2359296+294912+512)] = 0.f;
  }
}

// ---------------- transpose-cast vi/ir -> catseq[b][p][1024] bf16 ----------------
__global__ __launch_bounds__(256) void k_cat(const float* vi, const float* ir, bf16* cat)
{
  __shared__ float ld[32][129];
  int pt = blockIdx.x, ct = blockIdx.y, b = blockIdx.z;
  const float* src = (ct < 16) ? vi : ir;
  int c0 = (ct & 15) * 32;
  int tid = threadIdx.x;
  int p0 = pt * 128;
  for (int it = 0; it < 4; ++it) {
    int row = it*8 + (tid>>5);
    int pc  = (tid & 31) * 4;
    float4 v = *(const float4*)(src + ((long)(b*512 + c0 + row))*1024 + p0 + pc);
    ld[row][pc+0]=v.x; ld[row][pc+1]=v.y; ld[row][pc+2]=v.z; ld[row][pc+3]=v.w;
  }
  __syncthreads();
  int p = tid >> 1, half = tid & 1;
  bf16x8 o0, o1;
  #pragma unroll
  for (int j = 0; j < 8; ++j) o0[j] = (bf16)ld[half*16 + j][p];
  #pragma unroll
  for (int j = 0; j < 8; ++j) o1[j] = (bf16)ld[half*16 + 8 + j][p];
  long ccol = (ct<16 ? 0 : 512) + c0 + half*16;
  bf16* dst = cat + ((long)(b*1024 + p0 + p))*1024 + ccol;
  *(bf16x8*)dst       = o0;
  *((bf16x8*)dst + 1) = o1;
}

// ---------------- pooled[b][c] ----------------
__global__ __launch_bounds__(256) void k_pool(const float* vi, const float* ir, float* pooled)
{
  int bc = blockIdx.x;
  int tid = threadIdx.x;
  float4 a = ((const float4*)(vi + (long)bc*1024))[tid];
  float4 c = ((const float4*)(ir + (long)bc*1024))[tid];
  float s = a.x+a.y+a.z+a.w + c.x+c.y+c.z+c.w;
  #pragma unroll
  for (int off=32; off; off>>=1) s += __shfl_down(s, off);
  __shared__ float wsum[4];
  if ((tid&63)==0) wsum[tid>>6] = s;
  __syncthreads();
  if (tid==0) pooled[bc] = (wsum[0]+wsum[1]+wsum[2]+wsum[3]) * (1.f/1024.f);
}

// ---------------- mlp1: wave-per-row, coalesced w1 row reads ----------------
__global__ __launch_bounds__(256) void k_mlp1(const float* pooled, const float* w1, const float* b1, float* hid)
{
  __shared__ float pl[8*512];
  int tid = threadIdx.x;
  #pragma unroll
  for (int k=0;k<4;++k)
    ((float4*)pl)[tid + 256*k] = ((const float4*)pooled)[tid + 256*k];
  __syncthreads();
  int lane = tid&63, wave = tid>>6;
  #pragma unroll
  for (int rr=0; rr<4; ++rr) {
    int row = (blockIdx.x*4 + wave)*4 + rr;
    const float* wr = w1 + (long)row*512;
    float acc[8] = {};
    #pragma unroll
    for (int e=0;e<8;++e) {
      int c = lane + 64*e;
      float w = wr[c];
      #pragma unroll
      for (int b=0;b<8;++b) acc[b] += w * pl[b*512+c];
    }
    #pragma unroll
    for (int b=0;b<8;++b) {
      float s = acc[b];
      #pragma unroll
      for (int off=32; off; off>>=1) s += __shfl_down(s, off);
      if (lane==0) hid[b*2048 + row] = fmaxf(s + b1[row], 0.f);
    }
  }
}

// ---------------- mlp2a: one block per (b,j) logit ----------------
__global__ __launch_bounds__(256) void k_mlp2a(const float* hid, const float* w2, const float* b2, float* lg)
{
  int blk = blockIdx.x; int b = blk/25, j = blk%25;
  int tid = threadIdx.x, lane = tid&63, wave = tid>>6;
  const float4* h4 = (const float4*)(hid + b*2048);
  const float4* w4 = (const float4*)(w2 + (long)j*2048);
  float4 a0 = h4[tid*2], a1 = h4[tid*2+1];
  float4 c0 = w4[tid*2], c1 = w4[tid*2+1];
  float s = a0.x*c0.x+a0.y*c0.y+a0.z*c0.z+a0.w*c0.w
          + a1.x*c1.x+a1.y*c1.y+a1.z*c1.z+a1.w*c1.w;
  #pragma unroll
  for (int off=32; off; off>>=1) s += __shfl_down(s, off);
  __shared__ float wsum[4];
  if (lane==0) wsum[wave] = s;
  __syncthreads();
  if (tid==0) lg[b*25+j] = wsum[0]+wsum[1]+wsum[2]+wsum[3] + b2[j];
}

// ---------------- softmax over 25 logits -> kw[b][32] ----------------
__global__ __launch_bounds__(64) void k_smax(const float* lg, float* kw)
{
  int b = threadIdx.x;
  if (b < 8) {
    float mx = -1e30f;
    for (int j=0;j<25;++j) mx = fmaxf(mx, lg[b*25+j]);
    float e[25], s = 0.f;
    for (int j=0;j<25;++j){ e[j]=__expf(lg[b*25+j]-mx); s+=e[j]; }
    float inv = 1.f/s;
    for (int j=0;j<25;++j) kw[b*32+j] = e[j]*inv;
  }
}

// ---------------- generic TN bf16 MFMA GEMM (2-phase prefetch, XCD-chunked decode) ----------------
// OP 0: QKV   flat 768:  b=wg&7, which=wg>>8,        xy=(wg>>3)&31
// OP 1: Wo    flat 512:  b=wg&7, xy=wg>>3 (0..63)
// OP 2: enh   flat 512:  b=wg&7, kg=(wg>>3)>>5, xy=(wg>>3)&31
// OP 3: gate1 flat 288:  b=wg&7, tap=(wg>>3)>>2, x=(wg>>3)&3
template<int OP, int BM, int BN, int WAVES_M, int KSTEPS>
__global__ __launch_bounds__(256)
void k_gemm(KParams p)
{
  constexpr int WAVES_N = 4/WAVES_M;
  constexpr int MT = BM/(WAVES_M*16);
  constexpr int NT = BN/(WAVES_N*16);
  __shared__ bf16 As[2][BM*32];
  __shared__ bf16 Bs[2][BN*32];
  const int tid = threadIdx.x, lane = tid&63, wave = tid>>6;
  const int g = lane>>4, l15 = lane&15;
  const int wm = wave % WAVES_M, wn = wave / WAVES_M;

  int b, which = 0, tap = 0, kg = 0, m0, n0;
  const bf16 *Aptr, *Bptr;
  long ldb, lda;
  const int wg = blockIdx.x;
  if constexpr (OP==0) {
    b = wg&7; which = wg>>8;
    int xy = (wg>>3)&31;
    m0 = (xy>>3)*BM; n0 = (xy&7)*BN;
    Aptr = (const bf16*)(p.ws+OFF_WBF) + (long)which*262144;
    Bptr = (const bf16*)(p.ws+OFF_CATSEQ) + (long)b*1048576 + (which?512:0);
    ldb = 1024; lda = 512;
  } else if constexpr (OP==1) {
    b = wg&7;
    int xy = wg>>3;
    m0 = (xy>>3)*BM; n0 = (xy&7)*BN;
    Aptr = (const bf16*)(p.ws+OFF_WBF) + 3L*262144;
    Bptr = (const bf16*)(p.ws+OFF_CTX) + (long)b*524288;
    ldb = 512; lda = 512;
  } else if constexpr (OP==2) {
    b = wg&7;
    int loc = wg>>3;
    kg = loc>>5;
    int xy = loc&31;
    m0 = (xy>>3)*BM; n0 = (xy&7)*BN;
    Aptr = (const bf16*)(p.ws+OFF_ENHW);
    Bptr = (const bf16*)(p.ws+OFF_F2) + (long)b*524288;
    ldb = 512; lda = 512;
  } else {
    b = wg&7;
    int loc = wg>>3;
    tap = loc>>2;
    m0 = 0; n0 = (loc&3)*BN;
    Aptr = (const bf16*)(p.ws+OFF_GW1R) + (long)tap*32768;
    Bptr = (const bf16*)(p.ws+OFF_CATSEQ) + (long)b*1048576;
    ldb = 1024; lda = 1024;
  }
  const bf16* zp = (const bf16*)(p.ws+OFF_ZP);

  auto STAGE = [&](int buf, int ks) {
    int t, kc;
    if constexpr (OP==2) { int gks = kg*72 + ks; t = gks>>4; kc = gks&15; }
    else if constexpr (OP==3) { t = tap; kc = ks; }
    else { t = 0; kc = ks; }
    for (int c = tid; c < BM*4; c += 256) {
      int row = c>>2, slot = c&3;
      int ss = slot ^ ((row>>1)&3);
      const bf16* src;
      if constexpr (OP==2) src = Aptr + (long)t*262144 + (long)(m0+row)*lda + kc*32 + ss*8;
      else                 src = Aptr + (long)(m0+row)*lda + kc*32 + ss*8;
      gload16(src, As[buf] + (long)(c-lane)*8);
    }
    for (int c = tid; c < BN*4; c += 256) {
      int row = c>>2, slot = c&3;
      int ss = slot ^ ((row>>1)&3);
      const bf16* src;
      if constexpr (OP==2 || OP==3) {
        int pp = n0 + row;
        int hh = (pp>>5) + t/3 - 1, ww = (pp&31) + t%3 - 1;
        bool valid = ((unsigned)hh < 32u) && ((unsigned)ww < 32u);
        src = valid ? (Bptr + (long)(hh*32+ww)*ldb + kc*32 + ss*8) : zp;
      } else {
        src = Bptr + (long)(n0+row)*ldb + kc*32 + ss*8;
      }
      gload16(src, Bs[buf] + (long)(c-lane)*8);
    }
  };

  f32x4 acc[MT][NT] = {};

  STAGE(0, 0);
  __syncthreads();
  int cur = 0;
  #pragma unroll 2
  for (int ks = 0; ks < KSTEPS; ++ks) {
    if (ks+1 < KSTEPS) STAGE(cur^1, ks+1);
    bf16x8 af[MT], bq_[NT];
    #pragma unroll
    for (int mt=0; mt<MT; ++mt) {
      int row = wm*MT*16 + mt*16 + l15;
      af[mt] = *(const bf16x8*)&As[cur][row*32 + 8*(g ^ ((row>>1)&3))];
    }
    #pragma unroll
    for (int nt=0; nt<NT; ++nt) {
      int row = wn*NT*16 + nt*16 + l15;
      bq_[nt] = *(const bf16x8*)&Bs[cur][row*32 + 8*(g ^ ((row>>1)&3))];
    }
    __builtin_amdgcn_s_setprio(1);
    #pragma unroll
    for (int mt=0; mt<MT; ++mt)
      #pragma unroll
      for (int nt=0; nt<NT; ++nt)
        acc[mt][nt] = __builtin_amdgcn_mfma_f32_16x16x32_bf16(af[mt], bq_[nt], acc[mt][nt], 0,0,0);
    __builtin_amdgcn_s_setprio(0);
    __syncthreads();
    cur ^= 1;
  }

  #pragma unroll
  for (int mt=0; mt<MT; ++mt) {
    #pragma unroll
    for (int nt=0; nt<NT; ++nt) {
      #pragma unroll
      for (int reg=0; reg<4; ++reg) {
        int m = m0 + wm*MT*16 + mt*16 + 4*g + reg;
        int n = n0 + wn*NT*16 + nt*16 + l15;
        float v = acc[mt][nt][reg];
        if constexpr (OP==0) {
          const float* bias = which==0?p.bq: which==1?p.bk:p.bv;
          v += bias[m];
          if (which==0) v *= 0.125f;
          int h = m>>6, d = m&63;
          if (which==2) ((bf16*)(p.ws+OFF_VT))[((long)(b*8+h)*64 + d)*1024 + n] = (bf16)v;
          else {
            bf16* dst = (bf16*)(p.ws + (which==0?OFF_Q:OFF_K));
            dst[((long)(b*8+h)*1024 + n)*64 + d] = (bf16)v;
          }
        } else if constexpr (OP==1) {
          v += p.bo[m];
          ((bf16*)(p.ws+OFF_FF))[((long)(b*512+m))*1024 + n] = (bf16)v;
        } else if constexpr (OP==2) {
          float* part = (float*)(p.ws+OFF_Q) + (long)kg*4194304;
          part[((long)b*512+m)*1024 + n] = v;
        } else {
          ((float*)(p.ws+OFF_G1P))[((long)((tap*8+b)*32+m))*1024 + n] = v;
        }
      }
    }
  }
}

// ---------------- enh split-K reduce + BN + SiLU -> out ----------------
__global__ __launch_bounds__(256) void k_enhred(KParams p)
{
  long e = ((long)blockIdx.x*256 + threadIdx.x)*4;
  const float* part = (const float*)(p.ws+OFF_Q);
  float4 a = *(const float4*)(part + e);
  float4 c = *(const float4*)(part + 4194304 + e);
  int m = (int)((e>>10)&511);
  const float* chs = (const float*)(p.ws+OFF_CHS);
  float sc = chs[m], sh = chs[512+m];
  float4 o;
  float y0 = (a.x+c.x)*sc+sh, y1 = (a.y+c.y)*sc+sh, y2 = (a.z+c.z)*sc+sh, y3 = (a.w+c.w)*sc+sh;
  o.x = y0/(1.f+__expf(-y0)); o.y = y1/(1.f+__expf(-y1));
  o.z = y2/(1.f+__expf(-y2)); o.w = y3/(1.f+__expf(-y3));
  *(float4*)(p.out + e) = o;
}

// ---------------- flash attention (KVBLK=64, dbuf prefetch, defer-max, XCD-chunked) ----------------
__global__ __launch_bounds__(256)
void k_attn(KParams p)
{
  const bf16* Q = (const bf16*)(p.ws+OFF_Q);
  const bf16* K = (const bf16*)(p.ws+OFF_K);
  const bf16* V = (const bf16*)(p.ws+OFF_VT);
  bf16* ctx = (bf16*)(p.ws+OFF_CTX);
  int wg = blockIdx.x;
  int bh = (wg&7)*8 + (wg>>7);
  int qt = (wg>>3)&15;
  int b = bh>>3, h = bh&7;
  int tid = threadIdx.x, lane = tid&63, wave = tid>>6, g = lane>>4, l15 = lane&15;
  __shared__ bf16 Ks[2][64*64];
  __shared__ bf16 Vs[2][64*64];
  __shared__ bf16 Ps[4][16*64];
  const bf16* Qw = Q + ((long)bh*1024 + qt*64 + wave*16)*64;
  bf16x8 qf[2];
  qf[0] = *(const bf16x8*)(Qw + l15*64 + g*8);
  qf[1] = *(const bf16x8*)(Qw + l15*64 + 32 + g*8);
  const bf16* Kb = K + (long)bh*65536;
  const bf16* Vb = V + (long)bh*65536;
  float mr[4] = {-1e30f,-1e30f,-1e30f,-1e30f};
  float lr[4] = {0,0,0,0};
  f32x4 cacc[4] = {};

  auto STAGE = [&](int buf, int kv0) {
    #pragma unroll
    for (int c0 = 0; c0 < 512; c0 += 256) {
      int c = c0 + tid;
      int row = c>>3, slot = c&7, ss = slot ^ (row&7);
      gload16(Kb + (long)(kv0+row)*64 + ss*8, Ks[buf] + (long)(c-lane)*8);
    }
    #pragma unroll
    for (int c0 = 0; c0 < 512; c0 += 256) {
      int c = c0 + tid;
      int d = c>>3, slot = c&7, ss = slot ^ (d&7);
      gload16(Vb + (long)d*1024 + kv0 + ss*8, Vs[buf] + (long)(c-lane)*8);
    }
  };

  STAGE(0, 0);
  __syncthreads();
  int cur = 0;
  for (int step = 0; step < 16; ++step) {
    if (step < 15) STAGE(cur^1, (step+1)*64);
    f32x4 s0 = {}, s1 = {}, s2 = {}, s3 = {};
    __builtin_amdgcn_s_setprio(1);
    {
      int r0 = l15, r1 = 16+l15, r2 = 32+l15, r3 = 48+l15;
      #pragma unroll
      for (int ks2=0; ks2<2; ++ks2) {
        bf16x8 kf0 = *(const bf16x8*)&Ks[cur][r0*64 + 8*((4*ks2+g)^(r0&7))];
        bf16x8 kf1 = *(const bf16x8*)&Ks[cur][r1*64 + 8*((4*ks2+g)^(r1&7))];
        bf16x8 kf2 = *(const bf16x8*)&Ks[cur][r2*64 + 8*((4*ks2+g)^(r2&7))];
        bf16x8 kf3 = *(const bf16x8*)&Ks[cur][r3*64 + 8*((4*ks2+g)^(r3&7))];
        s0 = __builtin_amdgcn_mfma_f32_16x16x32_bf16(qf[ks2], kf0, s0, 0,0,0);
        s1 = __builtin_amdgcn_mfma_f32_16x16x32_bf16(qf[ks2], kf1, s1, 0,0,0);
        s2 = __builtin_amdgcn_mfma_f32_16x16x32_bf16(qf[ks2], kf2, s2, 0,0,0);
        s3 = __builtin_amdgcn_mfma_f32_16x16x32_bf16(qf[ks2], kf3, s3, 0,0,0);
      }
    }
    __builtin_amdgcn_s_setprio(0);
    float pmax[4];
    #pragma unroll
    for (int r=0;r<4;++r) {
      float x = fmaxf(fmaxf(s0[r],s1[r]), fmaxf(s2[r],s3[r]));
      x = fmaxf(x, __shfl_xor(x, 1));
      x = fmaxf(x, __shfl_xor(x, 2));
      x = fmaxf(x, __shfl_xor(x, 4));
      x = fmaxf(x, __shfl_xor(x, 8));
      pmax[r] = x;
    }
    bool need = (pmax[0] > mr[0]+8.f) | (pmax[1] > mr[1]+8.f) |
                (pmax[2] > mr[2]+8.f) | (pmax[3] > mr[3]+8.f);
    if (__any(need)) {
      #pragma unroll
      for (int r=0;r<4;++r) {
        float mn = fmaxf(mr[r], pmax[r]);
        float al = __expf(mr[r]-mn);
        mr[r] = mn; lr[r] *= al;
        cacc[0][r]*=al; cacc[1][r]*=al; cacc[2][r]*=al; cacc[3][r]*=al;
      }
    }
    bf16* Pw = Ps[wave];
    #pragma unroll
    for (int r=0;r<4;++r) {
      float p0 = __expf(s0[r]-mr[r]);
      float p1 = __expf(s1[r]-mr[r]);
      float p2 = __expf(s2[r]-mr[r]);
      float p3 = __expf(s3[r]-mr[r]);
      int q = 4*g + r;
      int xr = 8*(q&7);
      Pw[q*64 + ((     l15) ^ xr)] = (bf16)p0;
      Pw[q*64 + ((16 + l15) ^ xr)] = (bf16)p1;
      Pw[q*64 + ((32 + l15) ^ xr)] = (bf16)p2;
      Pw[q*64 + ((48 + l15) ^ xr)] = (bf16)p3;
      float sum = (p0+p1)+(p2+p3);
      sum += __shfl_xor(sum, 1);
      sum += __shfl_xor(sum, 2);
      sum += __shfl_xor(sum, 4);
      sum += __shfl_xor(sum, 8);
      lr[r] += sum;
    }
    bf16x8 pa0 = *(const bf16x8*)&Pw[l15*64 + 8*((  g)^(l15&7))];
    bf16x8 pa1 = *(const bf16x8*)&Pw[l15*64 + 8*((4+g)^(l15&7))];
    __builtin_amdgcn_s_setprio(1);
    #pragma unroll
    for (int nt=0;nt<4;++nt) {
      int d = nt*16 + l15;
      bf16x8 vf0 = *(const bf16x8*)&Vs[cur][d*64 + 8*((  g)^(d&7))];
      bf16x8 vf1 = *(const bf16x8*)&Vs[cur][d*64 + 8*((4+g)^(d&7))];
      cacc[nt] = __builtin_amdgcn_mfma_f32_16x16x32_bf16(pa0, vf0, cacc[nt], 0,0,0);
      cacc[nt] = __builtin_amdgcn_mfma_f32_16x16x32_bf16(pa1, vf1, cacc[nt], 0,0,0);
    }
    __builtin_amdgcn_s_setprio(0);
    __syncthreads();
    cur ^= 1;
  }
  #pragma unroll
  for (int nt=0;nt<4;++nt) {
    #pragma unroll
    for (int r=0;r<4;++r) {
      int q = qt*64 + wave*16 + 4*g + r;
      int cc = h*64 + nt*16 + l15;
      ctx[((long)(b*1024+q))*512 + cc] = (bf16)(cacc[nt][r] / lr[r]);
    }
  }
}

// ---------------- gate1 tap-partial reduce + bias + relu ----------------
__global__ __launch_bounds__(256) void k_g1red(KParams p)
{
  long o = (long)blockIdx.x*256 + threadIdx.x;   // [b][m][n], 262144
  const float* part = (const float*)(p.ws+OFF_G1P);
  int m = (int)((o >> 10) & 31);
  float a = p.gb1[m];
  #pragma unroll
  for (int t=0;t<9;++t) a += part[(long)t*262144 + o];
  ((float*)(p.ws+OFF_Y1))[o] = fmaxf(a, 0.f);
}

// ---------------- gate2 + sigmoid + sum -> gsum[b][p] ----------------
__global__ __launch_bounds__(256)
void k_g2(KParams p, const float* gw2, const float* gb2)
{
  __shared__ float st[3*32*32];
  __shared__ float sg[2][32];
  int h = blockIdx.x, b = blockIdx.y;
  const float* y1 = (const float*)(p.ws+OFF_Y1) + (long)b*32768;
  int tid = threadIdx.x;
  for (int c = tid; c < 768; c += 256) {
    int e = c*4;
    int hr = e>>10, hid = (e>>5)&31, w = e&31;
    int hh = h + hr - 1;
    float4 v = {0,0,0,0};
    if ((unsigned)hh < 32u) v = *(const float4*)(y1 + hid*1024 + hh*32 + w);
    *(float4*)&st[e] = v;
  }
  __syncthreads();
  if (tid < 64) {
    int gg = tid>>5, w = tid&31;
    float acc = gb2[gg];
    for (int hid=0; hid<32; ++hid) {
      #pragma unroll
      for (int u=0;u<3;++u) {
        #pragma unroll
        for (int v=0;v<3;++v) {
          int ww = w + v - 1;
          if ((unsigned)ww < 32u)
            acc += st[(u*32+hid)*32 + ww] * gw2[((gg*32+hid)*3+u)*3+v];
        }
      }
    }
    sg[gg][w] = 1.f/(1.f+__expf(-acc));
  }
  __syncthreads();
  if (tid < 32) ((float*)(p.ws+OFF_GSUM))[b*1024 + h*32 + tid] = sg[0][tid]+sg[1][tid];
}

// ---------------- dynamic 5x5 depthwise conv + gated fuse -> fused2[b][p][c] ----------------
__global__ __launch_bounds__(512)
void k_dyn(KParams p)
{
  __shared__ float ffs[16*1024];
  int ct = blockIdx.x;            // 0..31
  int b  = blockIdx.y;            // 0..7
  int c0 = ct*16;
  int t = threadIdx.x;            // 512
  const bf16* ffg = (const bf16*)(p.ws+OFF_FF) + ((long)(b*512 + c0))*1024;
  #pragma unroll
  for (int k2 = 0; k2 < 4; ++k2) {
    int chunk = t + 512*k2;
    int c = chunk >> 7, j = chunk & 127;
    bf16x8 v = *(const bf16x8*)(ffg + (long)c*1024 + j*8);
    float* d = ffs + c*1024 + j*8;
    #pragma unroll
    for (int e=0;e<8;++e) d[e] = (float)v[e];
  }
  const float* kwp = (const float*)(p.ws+OFF_KW) + b*32;
  float kk[25];
  #pragma unroll
  for (int j=0;j<25;++j) kk[j] = kwp[j];
  __syncthreads();
  int w = t & 31;
  int h0 = t >> 5;                // 0..15
  #pragma unroll
  for (int pass=0; pass<2; ++pass) {
    int h = h0 + pass*16;
    int pos = h*32 + w;
    float gsw = ((const float*)(p.ws+OFF_GSUM))[b*1024 + pos];
    const float* vip = p.vi + ((long)(b*512 + c0))*1024 + pos;
    const float* irp = p.ir + ((long)(b*512 + c0))*1024 + pos;
    bf16 outv[16];
    #pragma unroll
    for (int c=0;c<16;++c) {
      float dyn = 0.f;
      #pragma unroll
      for (int u=0;u<5;++u) {
        int hh = h+u-2;
        bool okh = (unsigned)hh < 32u;
        #pragma unroll
        for (int v=0;v<5;++v) {
          int ww = w+v-2;
          bool ok = okh && ((unsigned)ww < 32u);
          float fv = ffs[c*1024 + (hh&31)*32 + (ww&31)];
          dyn += (ok ? fv : 0.f) * kk[u*5+v];
        }
      }
      float val = gsw*dyn + vip[(long)c*1024] + irp[(long)c*1024];
      outv[c] = (bf16)val;
    }
    bf16* f2 = (bf16*)(p.ws+OFF_F2) + ((long)(b*1024 + pos))*512 + c0;
    *(bf16x8*)f2       = *(bf16x8*)&outv[0];
    *((bf16x8*)f2 + 1) = *(bf16x8*)&outv[8];
  }
}

extern "C" void kernel_launch(void* const* d_in, const int* in_sizes, int n_in,
                              void* d_out, int out_size, void* d_ws, size_t ws_size,
                              hipStream_t stream)
{
  char* ws = (char*)d_ws;
  KParams p;
  p.vi = (const float*)d_in[0];  p.ir = (const float*)d_in[1];
  p.bq = (const float*)d_in[7];  p.bk = (const float*)d_in[9];
  p.bv = (const float*)d_in[11]; p.bo = (const float*)d_in[13];
  p.gb1 = (const float*)d_in[15];
  p.ws = ws; p.out = (float*)d_out;

  k_wprep<<<14467,256,0,stream>>>((const float*)d_in[6],(const float*)d_in[8],(const float*)d_in[10],(const float*)d_in[12],
      (const float*)d_in[18],(const float*)d_in[14],(const float*)d_in[19],(const float*)d_in[20],(const float*)d_in[21],
      (const float*)d_in[22],(const float*)d_in[23],
      (bf16*)(ws+OFF_WBF),(bf16*)(ws+OFF_ENHW),(bf16*)(ws+OFF_GW1R),(float*)(ws+OFF_CHS),(float*)(ws+OFF_ZP));
  k_cat<<<dim3(8,32,8),256,0,stream>>>(p.vi, p.ir, (bf16*)(ws+OFF_CATSEQ));
  k_pool<<<4096,256,0,stream>>>(p.vi,p.ir,(float*)(ws+OFF_POOL));
  k_mlp1<<<128,256,0,stream>>>((const float*)(ws+OFF_POOL),(const float*)d_in[2],(const float*)d_in[3],(float*)(ws+OFF_HID));
  k_mlp2a<<<200,256,0,stream>>>((const float*)(ws+OFF_HID),(const float*)d_in[4],(const float*)d_in[5],(float*)(ws+OFF_G1P));
  k_smax<<<1,64,0,stream>>>((const float*)(ws+OFF_G1P),(float*)(ws+OFF_KW));
  k_gemm<0,128,128,2,16><<<768,256,0,stream>>>(p);
  k_attn<<<1024,256,0,stream>>>(p);
  k_gemm<1,64,128,2,16><<<512,256,0,stream>>>(p);
  k_gemm<3,32,256,1,32><<<288,256,0,stream>>>(p);
  k_g1red<<<1024,256,0,stream>>>(p);
  k_g2<<<dim3(32,8),256,0,stream>>>(p,(const float*)d_in[16],(const float*)d_in[17]);
  k_dyn<<<dim3(32,8),512,0,stream>>>(p);
  k_gemm<2,128,128,2,72><<<512,256,0,stream>>>(p);
  k_enhred<<<4096,256,0,stream>>>(p);
}